// Round 4
// baseline (841.101 us; speedup 1.0000x reference)
//
#include <hip/hip_runtime.h>
#include <hip/hip_bf16.h>
#include <math.h>

// CrossTransformerBlock3D: D=H=W=32, DIM=192, HEADS=12, HD=16, WS=2x2x2
// nW=4096 windows, N=8 queries/window, M=216 keys/window (3x3x3 neighborhood)
// K/V projected ONCE per base token (27x fewer KV FLOPs than reference).
// Attention = bf16 MFMA (16x16x32), one block per (window, 6-head half).

#define TOK 32768
#define NWIN 4096

typedef float f32x4 __attribute__((ext_vector_type(4)));
typedef short bf16x8 __attribute__((ext_vector_type(8)));
typedef short bf16x4 __attribute__((ext_vector_type(4)));

static __device__ __forceinline__ short f2bf(float x) {
  __hip_bfloat16 h = __float2bfloat16(x);
  return __builtin_bit_cast(short, h);
}

enum { EP_PLAIN = 0, EP_SPLIT = 1, EP_RESID = 2, EP_GELU = 3 };

// ---------------- LayerNorm: one wave per token, 4 tokens per block ----------
__global__ __launch_bounds__(256) void ln_kernel(const float* __restrict__ in,
                                                 float* __restrict__ out,
                                                 const float* __restrict__ g,
                                                 const float* __restrict__ b) {
  int token = blockIdx.x * 4 + (threadIdx.x >> 6);
  int lane = threadIdx.x & 63;
  const float* row = in + (size_t)token * 192;
  float v0 = row[lane], v1 = row[lane + 64], v2 = row[lane + 128];
  float s = v0 + v1 + v2;
#pragma unroll
  for (int off = 32; off; off >>= 1) s += __shfl_xor(s, off);
  float mean = s * (1.f / 192.f);
  float d0 = v0 - mean, d1 = v1 - mean, d2 = v2 - mean;
  float vs = d0 * d0 + d1 * d1 + d2 * d2;
#pragma unroll
  for (int off = 32; off; off >>= 1) vs += __shfl_xor(vs, off);
  float rstd = rsqrtf(vs * (1.f / 192.f) + 1e-5f);
  float* orow = out + (size_t)token * 192;
  orow[lane] = d0 * rstd * g[lane] + b[lane];
  orow[lane + 64] = d1 * rstd * g[lane + 64] + b[lane + 64];
  orow[lane + 128] = d2 * rstd * g[lane + 128] + b[lane + 128];
}

// ---------------- fp32 GEMM, 64x64 tile, 4x4 per-thread micro-tile ----------
template <int EPI, int K, int N>
__global__ __launch_bounds__(256) void gemm_ep(const float* __restrict__ A,
                                               const float* __restrict__ B,
                                               const float* __restrict__ bias,
                                               const float* __restrict__ resid,
                                               float* __restrict__ C0,
                                               float* __restrict__ C1) {
  __shared__ float As[16][68];
  __shared__ float Bs[16][68];
  const int tid = threadIdx.x;
  const int tx = tid & 15, ty = tid >> 4;
  const int rb = blockIdx.x * 64;
  const int nb = blockIdx.y * 64;
  float acc[4][4] = {};

#pragma unroll 1
  for (int k0 = 0; k0 < K; k0 += 16) {
#pragma unroll
    for (int p = 0; p < 4; ++p) {
      int idx = tid + p * 256;
      int kk = idx & 15, row = idx >> 4;
      As[kk][row] = A[(size_t)(rb + row) * K + k0 + kk];
    }
#pragma unroll
    for (int p = 0; p < 4; ++p) {
      int idx = tid + p * 256;
      int n = idx & 63, kk = idx >> 6;
      Bs[kk][n] = B[(size_t)(k0 + kk) * N + nb + n];
    }
    __syncthreads();
#pragma unroll
    for (int kk = 0; kk < 16; ++kk) {
      float a0 = As[kk][ty * 4 + 0], a1 = As[kk][ty * 4 + 1];
      float a2 = As[kk][ty * 4 + 2], a3 = As[kk][ty * 4 + 3];
      float b0 = Bs[kk][tx * 4 + 0], b1 = Bs[kk][tx * 4 + 1];
      float b2 = Bs[kk][tx * 4 + 2], b3 = Bs[kk][tx * 4 + 3];
      acc[0][0] += a0 * b0; acc[0][1] += a0 * b1; acc[0][2] += a0 * b2; acc[0][3] += a0 * b3;
      acc[1][0] += a1 * b0; acc[1][1] += a1 * b1; acc[1][2] += a1 * b2; acc[1][3] += a1 * b3;
      acc[2][0] += a2 * b0; acc[2][1] += a2 * b1; acc[2][2] += a2 * b2; acc[2][3] += a2 * b3;
      acc[3][0] += a3 * b0; acc[3][1] += a3 * b1; acc[3][2] += a3 * b2; acc[3][3] += a3 * b3;
    }
    __syncthreads();
  }

#pragma unroll
  for (int i = 0; i < 4; ++i) {
    int row = rb + ty * 4 + i;
#pragma unroll
    for (int j = 0; j < 4; ++j) {
      int col = nb + tx * 4 + j;
      float v = acc[i][j] + bias[col];
      if constexpr (EPI == EP_PLAIN) {
        C0[(size_t)row * N + col] = v;
      } else if constexpr (EPI == EP_SPLIT) {
        if (col < 192) C0[(size_t)row * 192 + col] = v;
        else           C1[(size_t)row * 192 + col - 192] = v;
      } else if constexpr (EPI == EP_RESID) {
        C0[(size_t)row * N + col] = v + resid[(size_t)row * N + col];
      } else if constexpr (EPI == EP_GELU) {
        C0[(size_t)row * N + col] = 0.5f * v * (1.f + erff(v * 0.70710678118654752f));
      }
    }
  }
}

// ---------------- Attention via bf16 MFMA ------------------------------------
// Block = (window, head-half): 384 threads = 6 waves, 1 head per wave.
// ph0: gather indices; Q direct global->frag
// ph1: K staging token-major [6][224][16] bf16, LINEAR vectorized b64 writes
// ph2: per-wave QK^T (14 MFMA); softmax in-register (exp2 w/ folded scale);
//      P (unnormalized) -> LDS via packed b32 pair writes (parity split)
// ph3: V staging token-major (same linear path, reuses K region, m>=216 zeroed)
// ph4: per-wave PV (7 MFMA) with ds_read_b64_tr_b16 B-frags; scale by 1/sum; store
__global__ __launch_bounds__(384, 3) void attn_mfma(const float* __restrict__ qbuf,
                                                    const float* __restrict__ kbuf,
                                                    const float* __restrict__ vbuf,
                                                    const float* __restrict__ bkv,
                                                    float* __restrict__ obuf) {
  __shared__ int tIdx[216];
  __shared__ __align__(16) short KVs[6 * 224 * 16];  // K, then V (token-major per head)
  __shared__ __align__(16) short Ps[6 * 8 * 232];    // P rows [q][tok], stride 232

  const int tid = threadIdx.x;
  const unsigned bx = blockIdx.x;
  const int b = ((bx & 7) << 9) | (bx >> 3);  // XCD-chunk swizzle (bijective: 8x512)
  const int hb = blockIdx.y * 6;
  const int ww = b & 15, wh = (b >> 4) & 15, wd = b >> 8;

  const int lane = tid & 63;
  const int hl = tid >> 6;                 // local head = wave
  const int lrow = lane & 15, lkg = lane >> 4;

  // ---- Q fragment: direct global load (A-frag: row=query lrow, k=ch lkg*8+j)
  bf16x8 qa = (bf16x8)0;
  if (lrow < 8 && lkg < 2) {
    int ldq = lrow >> 2, lhq = (lrow >> 1) & 1, lwq = lrow & 1;
    int tq = ((wd * 2 + ldq) * 32 + (wh * 2 + lhq)) * 32 + (ww * 2 + lwq);
    const float* qp = qbuf + (size_t)tq * 192 + (hb + hl) * 16 + lkg * 8;
    float4 lo = *(const float4*)qp;
    float4 hi = *(const float4*)(qp + 4);
    qa[0] = f2bf(lo.x); qa[1] = f2bf(lo.y); qa[2] = f2bf(lo.z); qa[3] = f2bf(lo.w);
    qa[4] = f2bf(hi.x); qa[5] = f2bf(hi.y); qa[6] = f2bf(hi.z); qa[7] = f2bf(hi.w);
  }

  // ---- ph0: neighborhood indices
  if (tid < 216) {
    int m = tid;
    int lw = m & 1;  int t1 = m >> 1;
    int dk = t1 % 3; int t2 = t1 / 3;
    int lh = t2 & 1; int t3 = t2 >> 1;
    int dj = t3 % 3; int t4 = t3 / 3;
    int ld = t4 & 1; int di = t4 >> 1;
    int nwd = wd + di - 1, nwh = wh + dj - 1, nww = ww + dk - 1;
    int slab = di * 9 + dj * 3 + dk;
    int t = -1;
    if (nwd >= 0 && nwd <= 15 && nwh >= 0 && nwh <= 15 && nww >= 0 && nww <= 15 && slab != 20) {
      int z = nwd * 2 + ld, y = nwh * 2 + lh, xx = nww * 2 + lw;
      t = (z * 32 + y) * 32 + xx;
    }
    tIdx[m] = t;
  }
  __syncthreads();

  // ---- ph1: K staging, token-major, perfectly linear b64 LDS writes
  for (unsigned idx = tid; idx < 6u * 224u * 4u; idx += 384u) {
    unsigned hlk = idx / 896u;
    unsigned rem = idx - hlk * 896u;
    unsigned m = rem >> 2;
    unsigned q4 = rem & 3u;  // channels q4*4..+3 of head hb+hlk
    bf16x4 kk = (bf16x4)0;
    if (m < 216u) {
      int t = tIdx[m];
      float4 k4 = (t >= 0) ? *(const float4*)(kbuf + (size_t)t * 192 + (hb + hlk) * 16 + q4 * 4)
                           : *(const float4*)(bkv + (hb + hlk) * 16 + q4 * 4);
      kk.x = f2bf(k4.x); kk.y = f2bf(k4.y); kk.z = f2bf(k4.z); kk.w = f2bf(k4.w);
    }
    *(bf16x4*)(KVs + (size_t)idx * 4u) = kk;  // = (hlk*224+m)*16 + q4*4
  }
  __syncthreads();

  // ---- ph2: QK^T + softmax + P write
  f32x4 s[14];
  const f32x4 zero4 = {0.f, 0.f, 0.f, 0.f};
  const short* Kh = KVs + hl * 3584;
#pragma unroll
  for (int t = 0; t < 14; ++t) {
    bf16x8 kf = (bf16x8)0;  // B-frag: col=token t*16+lrow, k=ch lkg*8+j
    if (lkg < 2) kf = *(const bf16x8*)(Kh + (t * 16 + lrow) * 16 + lkg * 8);
    s[t] = __builtin_amdgcn_mfma_f32_16x16x32_bf16(qa, kf, zero4, 0, 0, 0);
  }
  if (lrow >= 8) {  // mask padded tokens 216..223 (cols 8..15 of tile 13)
    s[13][0] = -1e30f; s[13][1] = -1e30f; s[13][2] = -1e30f; s[13][3] = -1e30f;
  }

  float inv[4];
  const float SCL = 0.25f * 1.44269504088896f;  // fold 1/sqrt(16) into exp2
#pragma unroll
  for (int r = 0; r < 4; ++r) {
    float mx = s[0][r];
#pragma unroll
    for (int t = 1; t < 14; ++t) mx = fmaxf(mx, s[t][r]);
    mx = fmaxf(mx, __shfl_xor(mx, 1));
    mx = fmaxf(mx, __shfl_xor(mx, 2));
    mx = fmaxf(mx, __shfl_xor(mx, 4));
    mx = fmaxf(mx, __shfl_xor(mx, 8));
    float sum = 0.f;
#pragma unroll
    for (int t = 0; t < 14; ++t) {
      float p = exp2f((s[t][r] - mx) * SCL);
      s[t][r] = p;  // unnormalized; normalize at epilogue
      sum += p;
    }
    sum += __shfl_xor(sum, 1);
    sum += __shfl_xor(sum, 2);
    sum += __shfl_xor(sum, 4);
    sum += __shfl_xor(sum, 8);
    inv[r] = 1.f / sum;
  }
  {
    // packed pair write: lane c pairs with c^1 via shfl; tile-parity split keeps
    // all 32 row-holding lanes busy; banks conflict-free by construction.
    short* Ph = Ps + hl * 8 * 232;
    const int rbase = (lane >> 4) * 4;
    const int cw = lrow & ~1;
#pragma unroll
    for (int r = 0; r < 4; ++r) {
#pragma unroll
      for (int t = 0; t < 14; ++t) {
        float self = s[t][r];
        float nbr = __shfl_xor(self, 1);
        if (lane < 32 && ((lane & 1) == (t & 1))) {
          float flo = (lane & 1) ? nbr : self;
          float fhi = (lane & 1) ? self : nbr;
          unsigned u = ((unsigned)(unsigned short)f2bf(fhi) << 16) |
                       (unsigned)(unsigned short)f2bf(flo);
          *(unsigned*)(Ph + (rbase + r) * 232 + t * 16 + cw) = u;
        }
      }
    }
  }
  __syncthreads();

  // ---- ph3: V staging, token-major, same linear path (reuses K region)
  for (unsigned idx = tid; idx < 6u * 224u * 4u; idx += 384u) {
    unsigned hlk = idx / 896u;
    unsigned rem = idx - hlk * 896u;
    unsigned m = rem >> 2;
    unsigned q4 = rem & 3u;
    bf16x4 vv = (bf16x4)0;  // m>=216 zeroed: no NaN enters PV
    if (m < 216u) {
      int t = tIdx[m];
      float4 v4 = (t >= 0) ? *(const float4*)(vbuf + (size_t)t * 192 + (hb + hlk) * 16 + q4 * 4)
                           : *(const float4*)(bkv + 192 + (hb + hlk) * 16 + q4 * 4);
      vv.x = f2bf(v4.x); vv.y = f2bf(v4.y); vv.z = f2bf(v4.z); vv.w = f2bf(v4.w);
    }
    *(bf16x4*)(KVs + (size_t)idx * 4u) = vv;
  }
  __syncthreads();

  // ---- ph4: PV with hardware-transpose B-frag reads
  // B-frag needs V[token T*32+lkg*8+j][ch lrow] from token-major LDS.
  // ds_read_b64_tr_b16 with per-lane fetch addr lkg*256 + (lrow>>2)*32 + (lane&3)*8
  // delivers exactly that (m156/m162 layout); wave fetch = 512B contiguous.
  unsigned vbase = (unsigned)(size_t)((__attribute__((address_space(3))) short*)KVs)
                 + (unsigned)(hl * 7168) + (unsigned)(lkg * 256 + (lrow >> 2) * 32 + (lane & 3) * 8);
  const short* PhA = Ps + (hl * 8 + lrow) * 232;
  f32x4 o = {0.f, 0.f, 0.f, 0.f};
#pragma unroll
  for (int T = 0; T < 7; ++T) {
    unsigned a = vbase + (unsigned)(T * 1024);
    bf16x4 t0, t1;
    asm volatile("ds_read_b64_tr_b16 %0, %1" : "=v"(t0) : "v"(a));
    asm volatile("ds_read_b64_tr_b16 %0, %1 offset:128" : "=v"(t1) : "v"(a));
    bf16x8 pa = (bf16x8)0;  // A-frag: row=query lrow (<8 real), k=token lkg*8+j
    if (lrow < 8) pa = *(const bf16x8*)(PhA + T * 32 + lkg * 8);
    asm volatile("s_waitcnt lgkmcnt(0)" ::: "memory");
    __builtin_amdgcn_sched_barrier(0);
    bf16x8 vf = __builtin_shufflevector(t0, t1, 0, 1, 2, 3, 4, 5, 6, 7);
    o = __builtin_amdgcn_mfma_f32_16x16x32_bf16(pa, vf, o, 0, 0, 0);
  }
  if (lane < 32) {
    const int h = hb + hl;
#pragma unroll
    for (int r = 0; r < 4; ++r) {
      int n = (lane >> 4) * 4 + r;
      int ldq = n >> 2, lhq = (n >> 1) & 1, lwq = n & 1;
      int tq = ((wd * 2 + ldq) * 32 + (wh * 2 + lhq)) * 32 + (ww * 2 + lwq);
      obuf[(size_t)tq * 192 + h * 16 + lrow] = o[r] * inv[r];
    }
  }
}

extern "C" void kernel_launch(void* const* d_in, const int* in_sizes, int n_in,
                              void* d_out, int out_size, void* d_ws, size_t ws_size,
                              hipStream_t stream) {
  const float* x   = (const float*)d_in[0];
  const float* xa  = (const float*)d_in[1];
  const float* n1g = (const float*)d_in[2];
  const float* n1b = (const float*)d_in[3];
  const float* n2g = (const float*)d_in[4];
  const float* n2b = (const float*)d_in[5];
  const float* Wq  = (const float*)d_in[6];
  const float* bq  = (const float*)d_in[7];
  const float* Wkv = (const float*)d_in[8];
  const float* bkv = (const float*)d_in[9];
  const float* Wp  = (const float*)d_in[10];
  const float* bp  = (const float*)d_in[11];
  const float* W1  = (const float*)d_in[12];
  const float* b1  = (const float*)d_in[13];
  const float* W2  = (const float*)d_in[14];
  const float* b2  = (const float*)d_in[15];

  float* ws = (float*)d_ws;
  const size_t TB = (size_t)TOK * 192;
  float* xn     = ws + 0 * TB;  // LN1(x)      -> later attn_out
  float* xan    = ws + 1 * TB;  // LN1(xa)     -> later x1
  float* qb     = ws + 2 * TB;  // Q           -> later LN2(x1)
  float* kb     = ws + 3 * TB;  // K           -> later mlp hidden (lo half)
  float* vb     = ws + 4 * TB;  // V           -> later mlp hidden (hi half)
  float* attn_o = xn;
  float* x1     = xan;
  float* xn2    = qb;
  float* hmlp   = kb;           // [TOK,384] spans kb..vb contiguously

  ln_kernel<<<TOK / 4, 256, 0, stream>>>(x, xn, n1g, n1b);
  ln_kernel<<<TOK / 4, 256, 0, stream>>>(xa, xan, n1g, n1b);

  gemm_ep<EP_PLAIN, 192, 192><<<dim3(TOK / 64, 3), 256, 0, stream>>>(xn, Wq, bq, nullptr, qb, nullptr);
  gemm_ep<EP_SPLIT, 192, 384><<<dim3(TOK / 64, 6), 256, 0, stream>>>(xan, Wkv, bkv, nullptr, kb, vb);

  attn_mfma<<<dim3(NWIN, 2), 384, 0, stream>>>(qb, kb, vb, bkv, attn_o);

  gemm_ep<EP_RESID, 192, 192><<<dim3(TOK / 64, 3), 256, 0, stream>>>(attn_o, Wp, bp, x, x1, nullptr);

  ln_kernel<<<TOK / 4, 256, 0, stream>>>(x1, xn2, n2g, n2b);

  gemm_ep<EP_GELU, 192, 384><<<dim3(TOK / 64, 6), 256, 0, stream>>>(xn2, W1, b1, nullptr, hmlp, nullptr);
  gemm_ep<EP_RESID, 384, 192><<<dim3(TOK / 64, 3), 256, 0, stream>>>(hmlp, W2, b2, x1, (float*)d_out, nullptr);
}

// Round 6
// 567.523 us; speedup vs baseline: 1.4821x; 1.4821x over previous
//
#include <hip/hip_runtime.h>
#include <hip/hip_bf16.h>
#include <math.h>

// CrossTransformerBlock3D: D=H=W=32, DIM=192, HEADS=12, HD=16, WS=2x2x2
// nW=4096 windows, N=8 queries/window, M=216 keys/window (3x3x3 neighborhood)
// K/V projected ONCE per base token (27x fewer KV FLOPs than reference).
// Attention: one wave per (window, head), barrier-free; bf16 MFMA 16x16x32.

#define TOK 32768
#define NWIN 4096

typedef float f32x4 __attribute__((ext_vector_type(4)));
typedef short bf16x8 __attribute__((ext_vector_type(8)));
typedef short bf16x4 __attribute__((ext_vector_type(4)));

static __device__ __forceinline__ short f2bf(float x) {
  __hip_bfloat16 h = __float2bfloat16(x);
  return __builtin_bit_cast(short, h);
}

enum { EP_PLAIN = 0, EP_SPLIT = 1, EP_RESID = 2, EP_GELU = 3 };

// ---------------- neighborhood index precompute: gIdx[4096][224] -------------
__global__ __launch_bounds__(256) void idx_kernel(int* __restrict__ gIdx) {
  int w = blockIdx.x;
  int m = threadIdx.x;
  if (m >= 224) return;
  int ww = w & 15, wh = (w >> 4) & 15, wd = w >> 8;
  int t = -1;
  if (m < 216) {
    int lw = m & 1;  int t1 = m >> 1;
    int dk = t1 % 3; int t2 = t1 / 3;
    int lh = t2 & 1; int t3 = t2 >> 1;
    int dj = t3 % 3; int t4 = t3 / 3;
    int ld = t4 & 1; int di = t4 >> 1;
    int nwd = wd + di - 1, nwh = wh + dj - 1, nww = ww + dk - 1;
    int slab = di * 9 + dj * 3 + dk;
    if (nwd >= 0 && nwd <= 15 && nwh >= 0 && nwh <= 15 && nww >= 0 && nww <= 15 && slab != 20) {
      t = ((nwd * 2 + ld) * 32 + (nwh * 2 + lh)) * 32 + (nww * 2 + lw);
    }
  }
  gIdx[w * 224 + m] = t;
}

// ---------------- LayerNorm: one wave per token, 4 tokens per block ----------
__global__ __launch_bounds__(256) void ln_kernel(const float* __restrict__ in,
                                                 float* __restrict__ out,
                                                 const float* __restrict__ g,
                                                 const float* __restrict__ b) {
  int token = blockIdx.x * 4 + (threadIdx.x >> 6);
  int lane = threadIdx.x & 63;
  const float* row = in + (size_t)token * 192;
  float v0 = row[lane], v1 = row[lane + 64], v2 = row[lane + 128];
  float s = v0 + v1 + v2;
#pragma unroll
  for (int off = 32; off; off >>= 1) s += __shfl_xor(s, off);
  float mean = s * (1.f / 192.f);
  float d0 = v0 - mean, d1 = v1 - mean, d2 = v2 - mean;
  float vs = d0 * d0 + d1 * d1 + d2 * d2;
#pragma unroll
  for (int off = 32; off; off >>= 1) vs += __shfl_xor(vs, off);
  float rstd = rsqrtf(vs * (1.f / 192.f) + 1e-5f);
  float* orow = out + (size_t)token * 192;
  orow[lane] = d0 * rstd * g[lane] + b[lane];
  orow[lane + 64] = d1 * rstd * g[lane + 64] + b[lane + 64];
  orow[lane + 128] = d2 * rstd * g[lane + 128] + b[lane + 128];
}

// ---------------- fp32 GEMM, 64x64 tile, 4x4 per-thread micro-tile ----------
template <int EPI, int K, int N>
__global__ __launch_bounds__(256) void gemm_ep(const float* __restrict__ A,
                                               const float* __restrict__ B,
                                               const float* __restrict__ bias,
                                               const float* __restrict__ resid,
                                               float* __restrict__ C0,
                                               float* __restrict__ C1) {
  __shared__ float As[16][68];
  __shared__ float Bs[16][68];
  const int tid = threadIdx.x;
  const int tx = tid & 15, ty = tid >> 4;
  const int rb = blockIdx.x * 64;
  const int nb = blockIdx.y * 64;
  float acc[4][4] = {};

#pragma unroll 1
  for (int k0 = 0; k0 < K; k0 += 16) {
#pragma unroll
    for (int p = 0; p < 4; ++p) {
      int idx = tid + p * 256;
      int kk = idx & 15, row = idx >> 4;
      As[kk][row] = A[(size_t)(rb + row) * K + k0 + kk];
    }
#pragma unroll
    for (int p = 0; p < 4; ++p) {
      int idx = tid + p * 256;
      int n = idx & 63, kk = idx >> 6;
      Bs[kk][n] = B[(size_t)(k0 + kk) * N + nb + n];
    }
    __syncthreads();
#pragma unroll
    for (int kk = 0; kk < 16; ++kk) {
      float a0 = As[kk][ty * 4 + 0], a1 = As[kk][ty * 4 + 1];
      float a2 = As[kk][ty * 4 + 2], a3 = As[kk][ty * 4 + 3];
      float b0 = Bs[kk][tx * 4 + 0], b1 = Bs[kk][tx * 4 + 1];
      float b2 = Bs[kk][tx * 4 + 2], b3 = Bs[kk][tx * 4 + 3];
      acc[0][0] += a0 * b0; acc[0][1] += a0 * b1; acc[0][2] += a0 * b2; acc[0][3] += a0 * b3;
      acc[1][0] += a1 * b0; acc[1][1] += a1 * b1; acc[1][2] += a1 * b2; acc[1][3] += a1 * b3;
      acc[2][0] += a2 * b0; acc[2][1] += a2 * b1; acc[2][2] += a2 * b2; acc[2][3] += a2 * b3;
      acc[3][0] += a3 * b0; acc[3][1] += a3 * b1; acc[3][2] += a3 * b2; acc[3][3] += a3 * b3;
    }
    __syncthreads();
  }

#pragma unroll
  for (int i = 0; i < 4; ++i) {
    int row = rb + ty * 4 + i;
#pragma unroll
    for (int j = 0; j < 4; ++j) {
      int col = nb + tx * 4 + j;
      float v = acc[i][j] + bias[col];
      if constexpr (EPI == EP_PLAIN) {
        C0[(size_t)row * N + col] = v;
      } else if constexpr (EPI == EP_SPLIT) {
        if (col < 192) C0[(size_t)row * 192 + col] = v;
        else           C1[(size_t)row * 192 + col - 192] = v;
      } else if constexpr (EPI == EP_RESID) {
        C0[(size_t)row * N + col] = v + resid[(size_t)row * N + col];
      } else if constexpr (EPI == EP_GELU) {
        C0[(size_t)row * N + col] = 0.5f * v * (1.f + erff(v * 0.70710678118654752f));
      }
    }
  }
}

// ---------------- Attention: 1 wave per (window, head), barrier-free ---------
// Block = 128 threads = 2 independent waves, private LDS slices.
// Per wave: tIdx <- gIdx (4 coalesced loads); Q,K frags direct from global;
// QK^T 14 MFMA; in-register softmax; P pair-packed to LDS; V staged token-major
// (linear b64); PV 7 MFMA with ds_read_b64_tr_b16 transpose B-frags.
__global__ __launch_bounds__(128, 3) void attn_mfma(const float* __restrict__ qbuf,
                                                    const float* __restrict__ kbuf,
                                                    const float* __restrict__ vbuf,
                                                    const float* __restrict__ bkv,
                                                    const int* __restrict__ gIdx,
                                                    float* __restrict__ obuf) {
  __shared__ int tIdxS[2][224];
  __shared__ __align__(16) short VsS[2][224 * 16];
  __shared__ __align__(16) short PsS[2][8 * 232];

  const int tid = threadIdx.x;
  const int wv = tid >> 6;        // wave in block
  const int lane = tid & 63;
  const int lrow = lane & 15, lkg = lane >> 4;

  // (window, head) from swizzled block id: 8 XCD chunks x 3072 blocks
  unsigned bid = blockIdx.x;
  unsigned u = (bid & 7u) * 3072u + (bid >> 3);   // bijective, 24576 blocks
  int w = (int)(u / 6u);
  int h = (int)(u % 6u) * 2 + wv;
  const int ww = w & 15, wh = (w >> 4) & 15, wd = w >> 8;

  int* tIdx = tIdxS[wv];
  short* Vs = VsS[wv];
  short* Ps = PsS[wv];

  // ---- stage tIdx (coalesced; wave-local, no barrier)
  {
    const int* src = gIdx + (size_t)w * 224;
#pragma unroll
    for (int k = 0; k < 4; ++k) {
      int i = lane + k * 64;
      if (i < 224) tIdx[i] = src[i];
    }
  }

  // ---- Q fragment direct from global (A-frag: row=query lrow, k=ch lkg*8+j)
  bf16x8 qa = (bf16x8)0;
  if (lrow < 8 && lkg < 2) {
    int ldq = lrow >> 2, lhq = (lrow >> 1) & 1, lwq = lrow & 1;
    int tq = ((wd * 2 + ldq) * 32 + (wh * 2 + lhq)) * 32 + (ww * 2 + lwq);
    const float* qp = qbuf + (size_t)tq * 192 + h * 16 + lkg * 8;
    float4 lo = *(const float4*)qp;
    float4 hi = *(const float4*)(qp + 4);
    qa[0] = f2bf(lo.x); qa[1] = f2bf(lo.y); qa[2] = f2bf(lo.z); qa[3] = f2bf(lo.w);
    qa[4] = f2bf(hi.x); qa[5] = f2bf(hi.y); qa[6] = f2bf(hi.z); qa[7] = f2bf(hi.w);
  }

  // ---- per-lane K token indices (LDS, 2-way broadcast reads)
  int ti[14];
#pragma unroll
  for (int T = 0; T < 14; ++T) ti[T] = tIdx[T * 16 + lrow];

  // ---- QK^T: K B-frags gathered directly from global
  f32x4 s[14];
  const f32x4 zero4 = {0.f, 0.f, 0.f, 0.f};
#pragma unroll
  for (int T = 0; T < 14; ++T) {
    bf16x8 kf = (bf16x8)0;  // B-frag: col=token T*16+lrow, k=ch lkg*8+j
    if (lkg < 2) {
      const float* kp = (ti[T] >= 0) ? kbuf + (size_t)ti[T] * 192 + h * 16 + lkg * 8
                                     : bkv + h * 16 + lkg * 8;
      float4 lo = *(const float4*)kp;
      float4 hi = *(const float4*)(kp + 4);
      kf[0] = f2bf(lo.x); kf[1] = f2bf(lo.y); kf[2] = f2bf(lo.z); kf[3] = f2bf(lo.w);
      kf[4] = f2bf(hi.x); kf[5] = f2bf(hi.y); kf[6] = f2bf(hi.z); kf[7] = f2bf(hi.w);
    }
    s[T] = __builtin_amdgcn_mfma_f32_16x16x32_bf16(qa, kf, zero4, 0, 0, 0);
  }
  if (lrow >= 8) {  // mask padded tokens 216..223 (cols 8..15 of tile 13)
    s[13][0] = -1e30f; s[13][1] = -1e30f; s[13][2] = -1e30f; s[13][3] = -1e30f;
  }

  // ---- softmax (in-register; 16-lane column groups)
  float inv[4];
  const float SCL = 0.25f * 1.44269504088896f;  // fold 1/sqrt(16) into exp2
#pragma unroll
  for (int r = 0; r < 4; ++r) {
    float mx = s[0][r];
#pragma unroll
    for (int t = 1; t < 14; ++t) mx = fmaxf(mx, s[t][r]);
    mx = fmaxf(mx, __shfl_xor(mx, 1));
    mx = fmaxf(mx, __shfl_xor(mx, 2));
    mx = fmaxf(mx, __shfl_xor(mx, 4));
    mx = fmaxf(mx, __shfl_xor(mx, 8));
    float sum = 0.f;
#pragma unroll
    for (int t = 0; t < 14; ++t) {
      float p = exp2f((s[t][r] - mx) * SCL);
      s[t][r] = p;  // unnormalized; normalize at epilogue
      sum += p;
    }
    sum += __shfl_xor(sum, 1);
    sum += __shfl_xor(sum, 2);
    sum += __shfl_xor(sum, 4);
    sum += __shfl_xor(sum, 8);
    inv[r] = 1.f / sum;
  }

  // ---- P -> LDS, pair-packed b32 writes (parity split, conflict-free)
  {
    const int rbase = (lane >> 4) * 4;
    const int cw = lrow & ~1;
#pragma unroll
    for (int r = 0; r < 4; ++r) {
#pragma unroll
      for (int t = 0; t < 14; ++t) {
        float self = s[t][r];
        float nbr = __shfl_xor(self, 1);
        if (lane < 32 && ((lane & 1) == (t & 1))) {
          float flo = (lane & 1) ? nbr : self;
          float fhi = (lane & 1) ? self : nbr;
          unsigned uu = ((unsigned)(unsigned short)f2bf(fhi) << 16) |
                        (unsigned)(unsigned short)f2bf(flo);
          *(unsigned*)(Ps + (rbase + r) * 232 + t * 16 + cw) = uu;
        }
      }
    }
  }

  // ---- V staging: token-major [224][16] bf16, linear b64 writes (wave-local)
#pragma unroll
  for (int k = 0; k < 14; ++k) {
    unsigned idx = (unsigned)lane + (unsigned)k * 64u;  // 0..895 b64-chunks
    unsigned m = idx >> 2, q4 = idx & 3u;
    bf16x4 vv = (bf16x4)0;  // m>=216 zeroed: no NaN enters PV
    if (m < 216u) {
      int t = tIdx[m];
      const float* vp = (t >= 0) ? vbuf + (size_t)t * 192 + h * 16 + q4 * 4
                                 : bkv + 192 + h * 16 + q4 * 4;
      float4 v4 = *(const float4*)vp;
      vv.x = f2bf(v4.x); vv.y = f2bf(v4.y); vv.z = f2bf(v4.z); vv.w = f2bf(v4.w);
    }
    *(bf16x4*)(Vs + idx * 4u) = vv;
  }
  // fence: ds_writes must complete before inline-asm tr reads
  asm volatile("s_waitcnt lgkmcnt(0)" ::: "memory");
  __builtin_amdgcn_sched_barrier(0);

  // ---- PV: batch all tr reads + P reads, single wait, then 7 MFMA
  unsigned vbase = (unsigned)(size_t)((__attribute__((address_space(3))) short*)Vs)
                 + (unsigned)(lkg * 256 + (lrow >> 2) * 32 + (lane & 3) * 8);
  bf16x4 t0[7], t1[7];
#pragma unroll
  for (int T = 0; T < 7; ++T) {
    unsigned a = vbase + (unsigned)(T * 1024);
    asm volatile("ds_read_b64_tr_b16 %0, %1" : "=v"(t0[T]) : "v"(a));
    asm volatile("ds_read_b64_tr_b16 %0, %1 offset:128" : "=v"(t1[T]) : "v"(a));
  }
  bf16x8 pa[7];
#pragma unroll
  for (int T = 0; T < 7; ++T) {
    pa[T] = (bf16x8)0;  // A-frag: row=query lrow (<8 real), k=token lkg*8+j
    if (lrow < 8) pa[T] = *(const bf16x8*)(Ps + lrow * 232 + T * 32 + lkg * 8);
  }
  asm volatile("s_waitcnt lgkmcnt(0)" ::: "memory");
  __builtin_amdgcn_sched_barrier(0);
  f32x4 o = {0.f, 0.f, 0.f, 0.f};
#pragma unroll
  for (int T = 0; T < 7; ++T) {
    bf16x8 vf = __builtin_shufflevector(t0[T], t1[T], 0, 1, 2, 3, 4, 5, 6, 7);
    o = __builtin_amdgcn_mfma_f32_16x16x32_bf16(pa[T], vf, o, 0, 0, 0);
  }

  // ---- store O (normalize by 1/sum here)
  if (lane < 32) {
#pragma unroll
    for (int r = 0; r < 4; ++r) {
      int n = (lane >> 4) * 4 + r;
      int ldq = n >> 2, lhq = (n >> 1) & 1, lwq = n & 1;
      int tq = ((wd * 2 + ldq) * 32 + (wh * 2 + lhq)) * 32 + (ww * 2 + lwq);
      obuf[(size_t)tq * 192 + h * 16 + lrow] = o[r] * inv[r];
    }
  }
}

extern "C" void kernel_launch(void* const* d_in, const int* in_sizes, int n_in,
                              void* d_out, int out_size, void* d_ws, size_t ws_size,
                              hipStream_t stream) {
  const float* x   = (const float*)d_in[0];
  const float* xa  = (const float*)d_in[1];
  const float* n1g = (const float*)d_in[2];
  const float* n1b = (const float*)d_in[3];
  const float* n2g = (const float*)d_in[4];
  const float* n2b = (const float*)d_in[5];
  const float* Wq  = (const float*)d_in[6];
  const float* bq  = (const float*)d_in[7];
  const float* Wkv = (const float*)d_in[8];
  const float* bkv = (const float*)d_in[9];
  const float* Wp  = (const float*)d_in[10];
  const float* bp  = (const float*)d_in[11];
  const float* W1  = (const float*)d_in[12];
  const float* b1  = (const float*)d_in[13];
  const float* W2  = (const float*)d_in[14];
  const float* b2  = (const float*)d_in[15];

  float* ws = (float*)d_ws;
  const size_t TB = (size_t)TOK * 192;
  float* xn     = ws + 0 * TB;  // LN1(x)      -> later attn_out
  float* xan    = ws + 1 * TB;  // LN1(xa)     -> later x1
  float* qb     = ws + 2 * TB;  // Q           -> later LN2(x1)
  float* kb     = ws + 3 * TB;  // K           -> later mlp hidden (lo half)
  float* vb     = ws + 4 * TB;  // V           -> later mlp hidden (hi half)
  int*   gIdx   = (int*)(ws + 5 * TB);  // [4096][224] neighborhood indices
  float* attn_o = xn;
  float* x1     = xan;
  float* xn2    = qb;
  float* hmlp   = kb;           // [TOK,384] spans kb..vb contiguously

  idx_kernel<<<NWIN, 256, 0, stream>>>(gIdx);

  ln_kernel<<<TOK / 4, 256, 0, stream>>>(x, xn, n1g, n1b);
  ln_kernel<<<TOK / 4, 256, 0, stream>>>(xa, xan, n1g, n1b);

  gemm_ep<EP_PLAIN, 192, 192><<<dim3(TOK / 64, 3), 256, 0, stream>>>(xn, Wq, bq, nullptr, qb, nullptr);
  gemm_ep<EP_SPLIT, 192, 384><<<dim3(TOK / 64, 6), 256, 0, stream>>>(xan, Wkv, bkv, nullptr, kb, vb);

  attn_mfma<<<NWIN * 6, 128, 0, stream>>>(qb, kb, vb, bkv, gIdx, attn_o);

  gemm_ep<EP_RESID, 192, 192><<<dim3(TOK / 64, 3), 256, 0, stream>>>(attn_o, Wp, bp, x, x1, nullptr);

  ln_kernel<<<TOK / 4, 256, 0, stream>>>(x1, xn2, n2g, n2b);

  gemm_ep<EP_GELU, 192, 384><<<dim3(TOK / 64, 6), 256, 0, stream>>>(xn2, W1, b1, nullptr, hmlp, nullptr);
  gemm_ep<EP_RESID, 384, 192><<<dim3(TOK / 64, 3), 256, 0, stream>>>(hmlp, W2, b2, x1, (float*)d_out, nullptr);
}

// Round 7
// 433.200 us; speedup vs baseline: 1.9416x; 1.3101x over previous
//
#include <hip/hip_runtime.h>
#include <hip/hip_bf16.h>
#include <math.h>

// CrossTransformerBlock3D: D=H=W=32, DIM=192, HEADS=12, HD=16, WS=2x2x2
// bf16 end-to-end interchange: LN->bf16, all GEMMs bf16-MFMA (A direct-frag
// loads, weights pre-packed in B-frag order), attention gathers bf16 K/V.
// Residual spine (x1, final out) stays fp32.

#define TOK 32768
#define NWIN 4096

typedef float f32x4 __attribute__((ext_vector_type(4)));
typedef short bf16x8 __attribute__((ext_vector_type(8)));
typedef short bf16x4 __attribute__((ext_vector_type(4)));

static __device__ __forceinline__ short f2bf(float x) {
  __hip_bfloat16 h = __float2bfloat16(x);
  return __builtin_bit_cast(short, h);
}

enum { EP_Q = 0, EP_KV = 1, EP_RESID = 2, EP_GELU = 3 };

// ---------------- weight pack: W[K][N] f32 -> MFMA B-frag order bf16 ---------
// dst[((c*(K/32)+ks)*64 + lane)*8 + j] = W[ks*32 + (lane>>4)*8 + j][c*16 + (lane&15)]
template <int K, int N>
__global__ __launch_bounds__(64) void pack_b(const float* __restrict__ W,
                                             short* __restrict__ dst) {
  const int blk = blockIdx.x;  // c*(K/32)+ks
  const int ks = blk % (K / 32), c = blk / (K / 32);
  const int lane = threadIdx.x;
  const int col = c * 16 + (lane & 15);
  const int krow = ks * 32 + (lane >> 4) * 8;
  bf16x8 v;
#pragma unroll
  for (int j = 0; j < 8; ++j) v[j] = f2bf(W[(size_t)(krow + j) * N + col]);
  *(bf16x8*)(dst + ((size_t)blk * 64 + lane) * 8) = v;
}

// ---------------- neighborhood indices + bkv bf16 cast -----------------------
__global__ __launch_bounds__(256) void idx_kernel(int* __restrict__ gIdx) {
  int w = blockIdx.x;
  int m = threadIdx.x;
  if (m >= 224) return;
  int ww = w & 15, wh = (w >> 4) & 15, wd = w >> 8;
  int t = -1;
  if (m < 216) {
    int lw = m & 1;  int t1 = m >> 1;
    int dk = t1 % 3; int t2 = t1 / 3;
    int lh = t2 & 1; int t3 = t2 >> 1;
    int dj = t3 % 3; int t4 = t3 / 3;
    int ld = t4 & 1; int di = t4 >> 1;
    int nwd = wd + di - 1, nwh = wh + dj - 1, nww = ww + dk - 1;
    int slab = di * 9 + dj * 3 + dk;
    if (nwd >= 0 && nwd <= 15 && nwh >= 0 && nwh <= 15 && nww >= 0 && nww <= 15 && slab != 20) {
      t = ((nwd * 2 + ld) * 32 + (nwh * 2 + lh)) * 32 + (nww * 2 + lw);
    }
  }
  gIdx[w * 224 + m] = t;
}

__global__ __launch_bounds__(384) void cast_bkv(const float* __restrict__ bkv,
                                                short* __restrict__ bkv_bf) {
  int i = threadIdx.x;
  bkv_bf[i] = f2bf(bkv[i]);
}

// ---------------- LayerNorm: f32 in -> bf16 out ------------------------------
__global__ __launch_bounds__(256) void ln_kernel(const float* __restrict__ in,
                                                 short* __restrict__ out,
                                                 const float* __restrict__ g,
                                                 const float* __restrict__ b) {
  int token = blockIdx.x * 4 + (threadIdx.x >> 6);
  int lane = threadIdx.x & 63;
  const float* row = in + (size_t)token * 192;
  float v0 = row[lane], v1 = row[lane + 64], v2 = row[lane + 128];
  float s = v0 + v1 + v2;
#pragma unroll
  for (int off = 32; off; off >>= 1) s += __shfl_xor(s, off);
  float mean = s * (1.f / 192.f);
  float d0 = v0 - mean, d1 = v1 - mean, d2 = v2 - mean;
  float vs = d0 * d0 + d1 * d1 + d2 * d2;
#pragma unroll
  for (int off = 32; off; off >>= 1) vs += __shfl_xor(vs, off);
  float rstd = rsqrtf(vs * (1.f / 192.f) + 1e-5f);
  short* orow = out + (size_t)token * 192;
  orow[lane] = f2bf(d0 * rstd * g[lane] + b[lane]);
  orow[lane + 64] = f2bf(d1 * rstd * g[lane + 64] + b[lane + 64]);
  orow[lane + 128] = f2bf(d2 * rstd * g[lane + 128] + b[lane + 128]);
}

// ---------------- bf16 MFMA GEMM --------------------------------------------
// A bf16 [M][K] row-major; Bp packed B-frags; 256 thr = 4 waves x 16 rows.
// Block covers 64 rows x 192 cols (grid.y splits N into 192-col halves).
// EP_Q:    C0 bf16 [M][192]
// EP_KV:   col<192 -> C0 bf16 [M][192], else C1 bf16 [M][192]
// EP_RESID:C0 f32 [M][NTOT] = acc + bias + resid
// EP_GELU: C0 bf16 [M][NTOT] = gelu(acc + bias)
template <int EPI, int K, int NTOT>
__global__ __launch_bounds__(256) void gemm_mfma(const short* __restrict__ A,
                                                 const short* __restrict__ Bp,
                                                 const float* __restrict__ bias,
                                                 const float* __restrict__ resid,
                                                 void* __restrict__ C0v,
                                                 void* __restrict__ C1v) {
  const int lane = threadIdx.x & 63;
  const int wv = threadIdx.x >> 6;
  const int lrow = lane & 15, lkg = lane >> 4;
  const int rb = blockIdx.x * 64 + wv * 16;
  const int nb = blockIdx.y * 192;
  const int nb16 = nb >> 4;

  f32x4 acc[12];
#pragma unroll
  for (int c = 0; c < 12; ++c) acc[c] = (f32x4){0.f, 0.f, 0.f, 0.f};

  const short* Arow = A + (size_t)(rb + lrow) * K + lkg * 8;
#pragma unroll
  for (int ks = 0; ks < K / 32; ++ks) {
    bf16x8 af = *(const bf16x8*)(Arow + ks * 32);
#pragma unroll
    for (int c = 0; c < 12; ++c) {
      bf16x8 bfr = *(const bf16x8*)(Bp + (((size_t)(nb16 + c) * (K / 32) + ks) * 64 + lane) * 8);
      acc[c] = __builtin_amdgcn_mfma_f32_16x16x32_bf16(af, bfr, acc[c], 0, 0, 0);
    }
  }

#pragma unroll
  for (int c = 0; c < 12; ++c) {
    int col = nb + c * 16 + lrow;
    float bia = bias[col];
#pragma unroll
    for (int i = 0; i < 4; ++i) {
      int row = rb + lkg * 4 + i;
      float v = acc[c][i] + bia;
      if constexpr (EPI == EP_Q) {
        ((short*)C0v)[(size_t)row * NTOT + col] = f2bf(v);
      } else if constexpr (EPI == EP_KV) {
        if (col < 192) ((short*)C0v)[(size_t)row * 192 + col] = f2bf(v);
        else           ((short*)C1v)[(size_t)row * 192 + col - 192] = f2bf(v);
      } else if constexpr (EPI == EP_RESID) {
        ((float*)C0v)[(size_t)row * NTOT + col] = v + resid[(size_t)row * NTOT + col];
      } else {  // EP_GELU
        float gg = 0.5f * v * (1.f + erff(v * 0.70710678118654752f));
        ((short*)C0v)[(size_t)row * NTOT + col] = f2bf(gg);
      }
    }
  }
}

// ---------------- Attention: 1 wave per (window, head), barrier-free ---------
// All inputs bf16. Q,K frags direct from global; V staged token-major in LDS;
// PV B-frags via ds_read_b64_tr_b16; in-register softmax; O stored bf16.
__global__ __launch_bounds__(128, 3) void attn_mfma(const short* __restrict__ qbuf,
                                                    const short* __restrict__ kbuf,
                                                    const short* __restrict__ vbuf,
                                                    const short* __restrict__ bkv_bf,
                                                    const int* __restrict__ gIdx,
                                                    short* __restrict__ obuf) {
  __shared__ int tIdxS[2][224];
  __shared__ __align__(16) short VsS[2][224 * 16];
  __shared__ __align__(16) short PsS[2][8 * 232];

  const int tid = threadIdx.x;
  const int wv = tid >> 6;
  const int lane = tid & 63;
  const int lrow = lane & 15, lkg = lane >> 4;

  unsigned bid = blockIdx.x;
  unsigned u = (bid & 7u) * 3072u + (bid >> 3);  // bijective, 24576 blocks
  int w = (int)(u / 6u);
  int h = (int)(u % 6u) * 2 + wv;
  const int ww = w & 15, wh = (w >> 4) & 15, wd = w >> 8;

  int* tIdx = tIdxS[wv];
  short* Vs = VsS[wv];
  short* Ps = PsS[wv];

  // stage tIdx (wave-local)
  {
    const int* src = gIdx + (size_t)w * 224;
#pragma unroll
    for (int k = 0; k < 4; ++k) {
      int i = lane + k * 64;
      if (i < 224) tIdx[i] = src[i];
    }
  }

  // Q fragment direct (bf16x8, 16B)
  bf16x8 qa = (bf16x8)0;
  if (lrow < 8 && lkg < 2) {
    int ldq = lrow >> 2, lhq = (lrow >> 1) & 1, lwq = lrow & 1;
    int tq = ((wd * 2 + ldq) * 32 + (wh * 2 + lhq)) * 32 + (ww * 2 + lwq);
    qa = *(const bf16x8*)(qbuf + (size_t)tq * 192 + h * 16 + lkg * 8);
  }

  int ti[14];
#pragma unroll
  for (int T = 0; T < 14; ++T) ti[T] = tIdx[T * 16 + lrow];

  // QK^T: K B-frags direct from global (bf16x8)
  f32x4 s[14];
  const f32x4 zero4 = {0.f, 0.f, 0.f, 0.f};
#pragma unroll
  for (int T = 0; T < 14; ++T) {
    bf16x8 kf = (bf16x8)0;
    if (lkg < 2) {
      const short* kp = (ti[T] >= 0) ? kbuf + (size_t)ti[T] * 192 + h * 16 + lkg * 8
                                     : bkv_bf + h * 16 + lkg * 8;
      kf = *(const bf16x8*)kp;
    }
    s[T] = __builtin_amdgcn_mfma_f32_16x16x32_bf16(qa, kf, zero4, 0, 0, 0);
  }
  if (lrow >= 8) {  // mask padded tokens 216..223
    s[13][0] = -1e30f; s[13][1] = -1e30f; s[13][2] = -1e30f; s[13][3] = -1e30f;
  }

  // softmax (in-register, 16-lane column groups)
  float inv[4];
  const float SCL = 0.25f * 1.44269504088896f;
#pragma unroll
  for (int r = 0; r < 4; ++r) {
    float mx = s[0][r];
#pragma unroll
    for (int t = 1; t < 14; ++t) mx = fmaxf(mx, s[t][r]);
    mx = fmaxf(mx, __shfl_xor(mx, 1));
    mx = fmaxf(mx, __shfl_xor(mx, 2));
    mx = fmaxf(mx, __shfl_xor(mx, 4));
    mx = fmaxf(mx, __shfl_xor(mx, 8));
    float sum = 0.f;
#pragma unroll
    for (int t = 0; t < 14; ++t) {
      float p = exp2f((s[t][r] - mx) * SCL);
      s[t][r] = p;
      sum += p;
    }
    sum += __shfl_xor(sum, 1);
    sum += __shfl_xor(sum, 2);
    sum += __shfl_xor(sum, 4);
    sum += __shfl_xor(sum, 8);
    inv[r] = 1.f / sum;
  }

  // P -> LDS, pair-packed b32 writes
  {
    const int rbase = (lane >> 4) * 4;
    const int cw = lrow & ~1;
#pragma unroll
    for (int r = 0; r < 4; ++r) {
#pragma unroll
      for (int t = 0; t < 14; ++t) {
        float self = s[t][r];
        float nbr = __shfl_xor(self, 1);
        if (lane < 32 && ((lane & 1) == (t & 1))) {
          float flo = (lane & 1) ? nbr : self;
          float fhi = (lane & 1) ? self : nbr;
          unsigned uu = ((unsigned)(unsigned short)f2bf(fhi) << 16) |
                        (unsigned)(unsigned short)f2bf(flo);
          *(unsigned*)(Ps + (rbase + r) * 232 + t * 16 + cw) = uu;
        }
      }
    }
  }

  // V staging: token-major [224][16] bf16, 8B loads -> 8B linear LDS writes
#pragma unroll
  for (int k = 0; k < 14; ++k) {
    unsigned idx = (unsigned)lane + (unsigned)k * 64u;
    unsigned m = idx >> 2, q4 = idx & 3u;
    bf16x4 vv = (bf16x4)0;
    if (m < 216u) {
      int t = tIdx[m];
      const short* vp = (t >= 0) ? vbuf + (size_t)t * 192 + h * 16 + q4 * 4
                                 : bkv_bf + 192 + h * 16 + q4 * 4;
      vv = *(const bf16x4*)vp;
    }
    *(bf16x4*)(Vs + idx * 4u) = vv;
  }
  asm volatile("s_waitcnt lgkmcnt(0)" ::: "memory");
  __builtin_amdgcn_sched_barrier(0);

  // PV: tr-reads + P frags, single wait, 7 MFMA
  unsigned vbase = (unsigned)(size_t)((__attribute__((address_space(3))) short*)Vs)
                 + (unsigned)(lkg * 256 + (lrow >> 2) * 32 + (lane & 3) * 8);
  bf16x4 t0[7], t1[7];
#pragma unroll
  for (int T = 0; T < 7; ++T) {
    unsigned a = vbase + (unsigned)(T * 1024);
    asm volatile("ds_read_b64_tr_b16 %0, %1" : "=v"(t0[T]) : "v"(a));
    asm volatile("ds_read_b64_tr_b16 %0, %1 offset:128" : "=v"(t1[T]) : "v"(a));
  }
  bf16x8 pa[7];
#pragma unroll
  for (int T = 0; T < 7; ++T) {
    pa[T] = (bf16x8)0;
    if (lrow < 8) pa[T] = *(const bf16x8*)(Ps + lrow * 232 + T * 32 + lkg * 8);
  }
  asm volatile("s_waitcnt lgkmcnt(0)" ::: "memory");
  __builtin_amdgcn_sched_barrier(0);
  f32x4 o = {0.f, 0.f, 0.f, 0.f};
#pragma unroll
  for (int T = 0; T < 7; ++T) {
    bf16x8 vf = __builtin_shufflevector(t0[T], t1[T], 0, 1, 2, 3, 4, 5, 6, 7);
    o = __builtin_amdgcn_mfma_f32_16x16x32_bf16(pa[T], vf, o, 0, 0, 0);
  }

  // store O (bf16, normalized)
  if (lane < 32) {
#pragma unroll
    for (int r = 0; r < 4; ++r) {
      int n = (lane >> 4) * 4 + r;
      int ldq = n >> 2, lhq = (n >> 1) & 1, lwq = n & 1;
      int tq = ((wd * 2 + ldq) * 32 + (wh * 2 + lhq)) * 32 + (ww * 2 + lwq);
      obuf[(size_t)tq * 192 + h * 16 + lrow] = f2bf(o[r] * inv[r]);
    }
  }
}

extern "C" void kernel_launch(void* const* d_in, const int* in_sizes, int n_in,
                              void* d_out, int out_size, void* d_ws, size_t ws_size,
                              hipStream_t stream) {
  const float* x   = (const float*)d_in[0];
  const float* xa  = (const float*)d_in[1];
  const float* n1g = (const float*)d_in[2];
  const float* n1b = (const float*)d_in[3];
  const float* n2g = (const float*)d_in[4];
  const float* n2b = (const float*)d_in[5];
  const float* Wq  = (const float*)d_in[6];
  const float* bq  = (const float*)d_in[7];
  const float* Wkv = (const float*)d_in[8];
  const float* bkv = (const float*)d_in[9];
  const float* Wp  = (const float*)d_in[10];
  const float* bp  = (const float*)d_in[11];
  const float* W1  = (const float*)d_in[12];
  const float* b1  = (const float*)d_in[13];
  const float* W2  = (const float*)d_in[14];
  const float* b2  = (const float*)d_in[15];

  char* wsb = (char*)d_ws;
  const size_t BB = (size_t)TOK * 192 * 2;  // 12.58 MB, one bf16 token buffer
  short* xn_bf  = (short*)(wsb + 0 * BB);   // LN1(x)   -> later attn_o (bf16)
  short* xan_bf = (short*)(wsb + 1 * BB);   // LN1(xa)  -> later LN2 out (bf16)
  short* qb     = (short*)(wsb + 2 * BB);   // Q bf16   -> later hmlp lo half
  short* kb     = (short*)(wsb + 3 * BB);   // K bf16   -> later hmlp hi half
  short* vb     = (short*)(wsb + 4 * BB);   // V bf16
  float* x1     = (float*)(wsb + 5 * BB);   // f32 [TOK][192]
  char* p = wsb + 5 * BB + (size_t)TOK * 192 * 4;
  int* gIdx = (int*)p;            p += (size_t)NWIN * 224 * 4;
  short* bkv_bf = (short*)p;      p += 1024;
  short* wq_p  = (short*)p;       p += 192 * 192 * 2;
  short* wkv_p = (short*)p;       p += 192 * 384 * 2;
  short* wp_p  = (short*)p;       p += 192 * 192 * 2;
  short* w1_p  = (short*)p;       p += 192 * 384 * 2;
  short* w2_p  = (short*)p;       p += 384 * 192 * 2;

  short* attn_o = xn_bf;
  short* xn2    = xan_bf;
  short* hmlp   = qb;  // [TOK][384] bf16 spans qb..kb

  // prep: indices + weight packs (graph-replayed each call; ~10 us total)
  idx_kernel<<<NWIN, 256, 0, stream>>>(gIdx);
  cast_bkv<<<1, 384, 0, stream>>>(bkv, bkv_bf);
  pack_b<192, 192><<<12 * 6, 64, 0, stream>>>(Wq, wq_p);
  pack_b<192, 384><<<24 * 6, 64, 0, stream>>>(Wkv, wkv_p);
  pack_b<192, 192><<<12 * 6, 64, 0, stream>>>(Wp, wp_p);
  pack_b<192, 384><<<24 * 6, 64, 0, stream>>>(W1, w1_p);
  pack_b<384, 192><<<12 * 12, 64, 0, stream>>>(W2, w2_p);

  ln_kernel<<<TOK / 4, 256, 0, stream>>>(x, xn_bf, n1g, n1b);
  ln_kernel<<<TOK / 4, 256, 0, stream>>>(xa, xan_bf, n1g, n1b);

  gemm_mfma<EP_Q, 192, 192><<<dim3(512, 1), 256, 0, stream>>>(xn_bf, wq_p, bq, nullptr, qb, nullptr);
  gemm_mfma<EP_KV, 192, 384><<<dim3(512, 2), 256, 0, stream>>>(xan_bf, wkv_p, bkv, nullptr, kb, vb);

  attn_mfma<<<NWIN * 6, 128, 0, stream>>>(qb, kb, vb, bkv_bf, gIdx, attn_o);

  gemm_mfma<EP_RESID, 192, 192><<<dim3(512, 1), 256, 0, stream>>>(attn_o, wp_p, bp, x, x1, nullptr);

  ln_kernel<<<TOK / 4, 256, 0, stream>>>(x1, xn2, n2g, n2b);

  gemm_mfma<EP_GELU, 192, 384><<<dim3(512, 2), 256, 0, stream>>>(xn2, w1_p, b1, nullptr, hmlp, nullptr);
  gemm_mfma<EP_RESID, 384, 192><<<dim3(512, 1), 256, 0, stream>>>(hmlp, w2_p, b2, x1, (float*)d_out, nullptr);
}

// Round 8
// 336.722 us; speedup vs baseline: 2.4979x; 1.2865x over previous
//
#include <hip/hip_runtime.h>
#include <hip/hip_bf16.h>
#include <math.h>

// CrossTransformerBlock3D: D=H=W=32, DIM=192, HEADS=12, HD=16, WS=2x2x2
// bf16 end-to-end interchange; all GEMMs bf16-MFMA; attention 1 wave per
// (window, head), barrier-free, with BATCHED gathers (kf[14]/vv[14] register
// arrays) so scattered L2 loads overlap instead of serializing (r7: VGPR=68
// forced 28 serial round-trips -> 14.7us wave lifetime).

#define TOK 32768
#define NWIN 4096

typedef float f32x4 __attribute__((ext_vector_type(4)));
typedef short bf16x8 __attribute__((ext_vector_type(8)));
typedef short bf16x4 __attribute__((ext_vector_type(4)));

static __device__ __forceinline__ short f2bf(float x) {
  __hip_bfloat16 h = __float2bfloat16(x);
  return __builtin_bit_cast(short, h);
}

enum { EP_Q = 0, EP_KV = 1, EP_RESID = 2, EP_GELU = 3 };

// ---------------- weight pack: W[K][N] f32 -> MFMA B-frag order bf16 ---------
template <int K, int N>
__global__ __launch_bounds__(64) void pack_b(const float* __restrict__ W,
                                             short* __restrict__ dst) {
  const int blk = blockIdx.x;  // c*(K/32)+ks
  const int ks = blk % (K / 32), c = blk / (K / 32);
  const int lane = threadIdx.x;
  const int col = c * 16 + (lane & 15);
  const int krow = ks * 32 + (lane >> 4) * 8;
  bf16x8 v;
#pragma unroll
  for (int j = 0; j < 8; ++j) v[j] = f2bf(W[(size_t)(krow + j) * N + col]);
  *(bf16x8*)(dst + ((size_t)blk * 64 + lane) * 8) = v;
}

// ---------------- neighborhood indices + bkv bf16 cast -----------------------
__global__ __launch_bounds__(256) void idx_kernel(int* __restrict__ gIdx) {
  int w = blockIdx.x;
  int m = threadIdx.x;
  if (m >= 224) return;
  int ww = w & 15, wh = (w >> 4) & 15, wd = w >> 8;
  int t = -1;
  if (m < 216) {
    int lw = m & 1;  int t1 = m >> 1;
    int dk = t1 % 3; int t2 = t1 / 3;
    int lh = t2 & 1; int t3 = t2 >> 1;
    int dj = t3 % 3; int t4 = t3 / 3;
    int ld = t4 & 1; int di = t4 >> 1;
    int nwd = wd + di - 1, nwh = wh + dj - 1, nww = ww + dk - 1;
    int slab = di * 9 + dj * 3 + dk;
    if (nwd >= 0 && nwd <= 15 && nwh >= 0 && nwh <= 15 && nww >= 0 && nww <= 15 && slab != 20) {
      t = ((nwd * 2 + ld) * 32 + (nwh * 2 + lh)) * 32 + (nww * 2 + lw);
    }
  }
  gIdx[w * 224 + m] = t;
}

__global__ __launch_bounds__(384) void cast_bkv(const float* __restrict__ bkv,
                                                short* __restrict__ bkv_bf) {
  int i = threadIdx.x;
  bkv_bf[i] = f2bf(bkv[i]);
}

// ---------------- LayerNorm: f32 in -> bf16 out ------------------------------
__global__ __launch_bounds__(256) void ln_kernel(const float* __restrict__ in,
                                                 short* __restrict__ out,
                                                 const float* __restrict__ g,
                                                 const float* __restrict__ b) {
  int token = blockIdx.x * 4 + (threadIdx.x >> 6);
  int lane = threadIdx.x & 63;
  const float* row = in + (size_t)token * 192;
  float v0 = row[lane], v1 = row[lane + 64], v2 = row[lane + 128];
  float s = v0 + v1 + v2;
#pragma unroll
  for (int off = 32; off; off >>= 1) s += __shfl_xor(s, off);
  float mean = s * (1.f / 192.f);
  float d0 = v0 - mean, d1 = v1 - mean, d2 = v2 - mean;
  float vs = d0 * d0 + d1 * d1 + d2 * d2;
#pragma unroll
  for (int off = 32; off; off >>= 1) vs += __shfl_xor(vs, off);
  float rstd = rsqrtf(vs * (1.f / 192.f) + 1e-5f);
  short* orow = out + (size_t)token * 192;
  orow[lane] = f2bf(d0 * rstd * g[lane] + b[lane]);
  orow[lane + 64] = f2bf(d1 * rstd * g[lane + 64] + b[lane + 64]);
  orow[lane + 128] = f2bf(d2 * rstd * g[lane + 128] + b[lane + 128]);
}

// ---------------- bf16 MFMA GEMM --------------------------------------------
template <int EPI, int K, int NTOT>
__global__ __launch_bounds__(256) void gemm_mfma(const short* __restrict__ A,
                                                 const short* __restrict__ Bp,
                                                 const float* __restrict__ bias,
                                                 const float* __restrict__ resid,
                                                 void* __restrict__ C0v,
                                                 void* __restrict__ C1v) {
  const int lane = threadIdx.x & 63;
  const int wv = threadIdx.x >> 6;
  const int lrow = lane & 15, lkg = lane >> 4;
  const int rb = blockIdx.x * 64 + wv * 16;
  const int nb = blockIdx.y * 192;
  const int nb16 = nb >> 4;

  f32x4 acc[12];
#pragma unroll
  for (int c = 0; c < 12; ++c) acc[c] = (f32x4){0.f, 0.f, 0.f, 0.f};

  const short* Arow = A + (size_t)(rb + lrow) * K + lkg * 8;
#pragma unroll
  for (int ks = 0; ks < K / 32; ++ks) {
    bf16x8 af = *(const bf16x8*)(Arow + ks * 32);
#pragma unroll
    for (int c = 0; c < 12; ++c) {
      bf16x8 bfr = *(const bf16x8*)(Bp + (((size_t)(nb16 + c) * (K / 32) + ks) * 64 + lane) * 8);
      acc[c] = __builtin_amdgcn_mfma_f32_16x16x32_bf16(af, bfr, acc[c], 0, 0, 0);
    }
  }

#pragma unroll
  for (int c = 0; c < 12; ++c) {
    int col = nb + c * 16 + lrow;
    float bia = bias[col];
#pragma unroll
    for (int i = 0; i < 4; ++i) {
      int row = rb + lkg * 4 + i;
      float v = acc[c][i] + bia;
      if constexpr (EPI == EP_Q) {
        ((short*)C0v)[(size_t)row * NTOT + col] = f2bf(v);
      } else if constexpr (EPI == EP_KV) {
        if (col < 192) ((short*)C0v)[(size_t)row * 192 + col] = f2bf(v);
        else           ((short*)C1v)[(size_t)row * 192 + col - 192] = f2bf(v);
      } else if constexpr (EPI == EP_RESID) {
        ((float*)C0v)[(size_t)row * NTOT + col] = v + resid[(size_t)row * NTOT + col];
      } else {  // EP_GELU
        float gg = 0.5f * v * (1.f + erff(v * 0.70710678118654752f));
        ((short*)C0v)[(size_t)row * NTOT + col] = f2bf(gg);
      }
    }
  }
}

// ---------------- Attention: 1 wave per (window, head), barrier-free ---------
// Batched gathers: ti[14]/mv[14] index prefetch from global gIdx, kf[14] K
// frags issued back-to-back before QK^T, vv[14] V loads issued BEFORE softmax
// (latency hides under softmax VALU + P-pack). LDS = V + P only (21.75 KB).
__global__ __launch_bounds__(128, 3) void attn_mfma(const short* __restrict__ qbuf,
                                                    const short* __restrict__ kbuf,
                                                    const short* __restrict__ vbuf,
                                                    const short* __restrict__ bkv_bf,
                                                    const int* __restrict__ gIdx,
                                                    short* __restrict__ obuf) {
  __shared__ __align__(16) short VsS[2][224 * 16];
  __shared__ __align__(16) short PsS[2][8 * 232];

  const int tid = threadIdx.x;
  const int wv = tid >> 6;
  const int lane = tid & 63;
  const int lrow = lane & 15, lkg = lane >> 4;

  unsigned bid = blockIdx.x;
  unsigned u = (bid & 7u) * 3072u + (bid >> 3);  // bijective, 24576 blocks
  int w = (int)(u / 6u);
  int h = (int)(u % 6u) * 2 + wv;
  const int ww = w & 15, wh = (w >> 4) & 15, wd = w >> 8;

  short* Vs = VsS[wv];
  short* Ps = PsS[wv];
  const int* gw = gIdx + (size_t)w * 224;

  // ---- index prefetch (batched 4B global loads, L2-resident table)
  int ti[14];
#pragma unroll
  for (int T = 0; T < 14; ++T) ti[T] = gw[T * 16 + lrow];
  int mv[14];
#pragma unroll
  for (int k = 0; k < 14; ++k) mv[k] = gw[(lane >> 2) + k * 16];

  // ---- Q fragment direct (bf16x8, 16B)
  bf16x8 qa = (bf16x8)0;
  if (lrow < 8 && lkg < 2) {
    int ldq = lrow >> 2, lhq = (lrow >> 1) & 1, lwq = lrow & 1;
    int tq = ((wd * 2 + ldq) * 32 + (wh * 2 + lhq)) * 32 + (ww * 2 + lwq);
    qa = *(const bf16x8*)(qbuf + (size_t)tq * 192 + h * 16 + lkg * 8);
  }

  // ---- K frags: all 14 gathers issued back-to-back (MLP!)
  bf16x8 kf[14];
#pragma unroll
  for (int T = 0; T < 14; ++T) {
    kf[T] = (bf16x8)0;
    if (lkg < 2) {
      const short* kp = (ti[T] >= 0) ? kbuf + (size_t)ti[T] * 192 + h * 16 + lkg * 8
                                     : bkv_bf + h * 16 + lkg * 8;
      kf[T] = *(const bf16x8*)kp;
    }
  }

  // ---- QK^T
  f32x4 s[14];
  const f32x4 zero4 = {0.f, 0.f, 0.f, 0.f};
#pragma unroll
  for (int T = 0; T < 14; ++T)
    s[T] = __builtin_amdgcn_mfma_f32_16x16x32_bf16(qa, kf[T], zero4, 0, 0, 0);
  if (lrow >= 8) {  // mask padded tokens 216..223
    s[13][0] = -1e30f; s[13][1] = -1e30f; s[13][2] = -1e30f; s[13][3] = -1e30f;
  }

  // ---- V loads issued NOW; latency hides under softmax + P-pack
  const int q4c = (lane & 3) * 4;  // this lane's channel quad
  bf16x4 vv[14];
#pragma unroll
  for (int k = 0; k < 14; ++k) {
    const short* vp = (mv[k] >= 0) ? vbuf + (size_t)mv[k] * 192 + h * 16 + q4c
                                   : bkv_bf + 192 + h * 16 + q4c;
    vv[k] = *(const bf16x4*)vp;  // P for padded tokens is exactly 0, bkv is safe
  }

  // ---- softmax (in-register, 16-lane column groups)
  float inv[4];
  const float SCL = 0.25f * 1.44269504088896f;
#pragma unroll
  for (int r = 0; r < 4; ++r) {
    float mx = s[0][r];
#pragma unroll
    for (int t = 1; t < 14; ++t) mx = fmaxf(mx, s[t][r]);
    mx = fmaxf(mx, __shfl_xor(mx, 1));
    mx = fmaxf(mx, __shfl_xor(mx, 2));
    mx = fmaxf(mx, __shfl_xor(mx, 4));
    mx = fmaxf(mx, __shfl_xor(mx, 8));
    float sum = 0.f;
#pragma unroll
    for (int t = 0; t < 14; ++t) {
      float p = exp2f((s[t][r] - mx) * SCL);
      s[t][r] = p;
      sum += p;
    }
    sum += __shfl_xor(sum, 1);
    sum += __shfl_xor(sum, 2);
    sum += __shfl_xor(sum, 4);
    sum += __shfl_xor(sum, 8);
    inv[r] = 1.f / sum;
  }

  // ---- P -> LDS, pair-packed b32 writes
  {
    const int rbase = (lane >> 4) * 4;
    const int cw = lrow & ~1;
#pragma unroll
    for (int r = 0; r < 4; ++r) {
#pragma unroll
      for (int t = 0; t < 14; ++t) {
        float self = s[t][r];
        float nbr = __shfl_xor(self, 1);
        if (lane < 32 && ((lane & 1) == (t & 1))) {
          float flo = (lane & 1) ? nbr : self;
          float fhi = (lane & 1) ? self : nbr;
          unsigned uu = ((unsigned)(unsigned short)f2bf(fhi) << 16) |
                        (unsigned)(unsigned short)f2bf(flo);
          *(unsigned*)(Ps + (rbase + r) * 232 + t * 16 + cw) = uu;
        }
      }
    }
  }

  // ---- V -> LDS (token-major [224][16]), linear 8B writes
#pragma unroll
  for (int k = 0; k < 14; ++k)
    *(bf16x4*)(Vs + ((unsigned)lane + (unsigned)k * 64u) * 4u) = vv[k];
  asm volatile("s_waitcnt lgkmcnt(0)" ::: "memory");
  __builtin_amdgcn_sched_barrier(0);

  // ---- PV: tr-reads + P frags, single wait, 7 MFMA
  unsigned vbase = (unsigned)(size_t)((__attribute__((address_space(3))) short*)Vs)
                 + (unsigned)(lkg * 256 + (lrow >> 2) * 32 + (lane & 3) * 8);
  bf16x4 t0[7], t1[7];
#pragma unroll
  for (int T = 0; T < 7; ++T) {
    unsigned a = vbase + (unsigned)(T * 1024);
    asm volatile("ds_read_b64_tr_b16 %0, %1" : "=v"(t0[T]) : "v"(a));
    asm volatile("ds_read_b64_tr_b16 %0, %1 offset:128" : "=v"(t1[T]) : "v"(a));
  }
  bf16x8 pa[7];
#pragma unroll
  for (int T = 0; T < 7; ++T) {
    pa[T] = (bf16x8)0;
    if (lrow < 8) pa[T] = *(const bf16x8*)(Ps + lrow * 232 + T * 32 + lkg * 8);
  }
  asm volatile("s_waitcnt lgkmcnt(0)" ::: "memory");
  __builtin_amdgcn_sched_barrier(0);
  f32x4 o = {0.f, 0.f, 0.f, 0.f};
#pragma unroll
  for (int T = 0; T < 7; ++T) {
    bf16x8 vf = __builtin_shufflevector(t0[T], t1[T], 0, 1, 2, 3, 4, 5, 6, 7);
    o = __builtin_amdgcn_mfma_f32_16x16x32_bf16(pa[T], vf, o, 0, 0, 0);
  }

  // ---- store O (bf16, normalized)
  if (lane < 32) {
#pragma unroll
    for (int r = 0; r < 4; ++r) {
      int n = (lane >> 4) * 4 + r;
      int ldq = n >> 2, lhq = (n >> 1) & 1, lwq = n & 1;
      int tq = ((wd * 2 + ldq) * 32 + (wh * 2 + lhq)) * 32 + (ww * 2 + lwq);
      obuf[(size_t)tq * 192 + h * 16 + lrow] = f2bf(o[r] * inv[r]);
    }
  }
}

extern "C" void kernel_launch(void* const* d_in, const int* in_sizes, int n_in,
                              void* d_out, int out_size, void* d_ws, size_t ws_size,
                              hipStream_t stream) {
  const float* x   = (const float*)d_in[0];
  const float* xa  = (const float*)d_in[1];
  const float* n1g = (const float*)d_in[2];
  const float* n1b = (const float*)d_in[3];
  const float* n2g = (const float*)d_in[4];
  const float* n2b = (const float*)d_in[5];
  const float* Wq  = (const float*)d_in[6];
  const float* bq  = (const float*)d_in[7];
  const float* Wkv = (const float*)d_in[8];
  const float* bkv = (const float*)d_in[9];
  const float* Wp  = (const float*)d_in[10];
  const float* bp  = (const float*)d_in[11];
  const float* W1  = (const float*)d_in[12];
  const float* b1  = (const float*)d_in[13];
  const float* W2  = (const float*)d_in[14];
  const float* b2  = (const float*)d_in[15];

  char* wsb = (char*)d_ws;
  const size_t BB = (size_t)TOK * 192 * 2;  // 12.58 MB, one bf16 token buffer
  short* xn_bf  = (short*)(wsb + 0 * BB);   // LN1(x)   -> later attn_o (bf16)
  short* xan_bf = (short*)(wsb + 1 * BB);   // LN1(xa)  -> later LN2 out (bf16)
  short* qb     = (short*)(wsb + 2 * BB);   // Q bf16   -> later hmlp lo half
  short* kb     = (short*)(wsb + 3 * BB);   // K bf16   -> later hmlp hi half
  short* vb     = (short*)(wsb + 4 * BB);   // V bf16
  float* x1     = (float*)(wsb + 5 * BB);   // f32 [TOK][192]
  char* p = wsb + 5 * BB + (size_t)TOK * 192 * 4;
  int* gIdx = (int*)p;            p += (size_t)NWIN * 224 * 4;
  short* bkv_bf = (short*)p;      p += 1024;
  short* wq_p  = (short*)p;       p += 192 * 192 * 2;
  short* wkv_p = (short*)p;       p += 192 * 384 * 2;
  short* wp_p  = (short*)p;       p += 192 * 192 * 2;
  short* w1_p  = (short*)p;       p += 192 * 384 * 2;
  short* w2_p  = (short*)p;       p += 384 * 192 * 2;

  short* attn_o = xn_bf;
  short* xn2    = xan_bf;
  short* hmlp   = qb;  // [TOK][384] bf16 spans qb..kb

  idx_kernel<<<NWIN, 256, 0, stream>>>(gIdx);
  cast_bkv<<<1, 384, 0, stream>>>(bkv, bkv_bf);
  pack_b<192, 192><<<12 * 6, 64, 0, stream>>>(Wq, wq_p);
  pack_b<192, 384><<<24 * 6, 64, 0, stream>>>(Wkv, wkv_p);
  pack_b<192, 192><<<12 * 6, 64, 0, stream>>>(Wp, wp_p);
  pack_b<192, 384><<<24 * 6, 64, 0, stream>>>(W1, w1_p);
  pack_b<384, 192><<<12 * 12, 64, 0, stream>>>(W2, w2_p);

  ln_kernel<<<TOK / 4, 256, 0, stream>>>(x, xn_bf, n1g, n1b);
  ln_kernel<<<TOK / 4, 256, 0, stream>>>(xa, xan_bf, n1g, n1b);

  gemm_mfma<EP_Q, 192, 192><<<dim3(512, 1), 256, 0, stream>>>(xn_bf, wq_p, bq, nullptr, qb, nullptr);
  gemm_mfma<EP_KV, 192, 384><<<dim3(512, 2), 256, 0, stream>>>(xan_bf, wkv_p, bkv, nullptr, kb, vb);

  attn_mfma<<<NWIN * 6, 128, 0, stream>>>(qb, kb, vb, bkv_bf, gIdx, attn_o);

  gemm_mfma<EP_RESID, 192, 192><<<dim3(512, 1), 256, 0, stream>>>(attn_o, wp_p, bp, x, x1, nullptr);

  ln_kernel<<<TOK / 4, 256, 0, stream>>>(x1, xn2, n2g, n2b);

  gemm_mfma<EP_GELU, 192, 384><<<dim3(512, 2), 256, 0, stream>>>(xn2, w1_p, b1, nullptr, hmlp, nullptr);
  gemm_mfma<EP_RESID, 384, 192><<<dim3(512, 1), 256, 0, stream>>>(hmlp, w2_p, b2, x1, (float*)d_out, nullptr);
}

// Round 9
// 263.386 us; speedup vs baseline: 3.1934x; 1.2784x over previous
//
#include <hip/hip_runtime.h>
#include <hip/hip_bf16.h>
#include <math.h>

// CrossTransformerBlock3D: D=H=W=32, DIM=192, HEADS=12, HD=16, WS=2x2x2
// bf16-MFMA everywhere. LN1 fused as GEMM prologue (Q,KV), LN2 fused as
// P-GEMM epilogue. K/V buffers extended by one row (=bkv projection) so the
// attention gather is branch-free (idx table stores resolved rows).

#define TOK 32768
#define NWIN 4096

typedef float f32x4 __attribute__((ext_vector_type(4)));
typedef short bf16x8 __attribute__((ext_vector_type(8)));
typedef short bf16x4 __attribute__((ext_vector_type(4)));

static __device__ __forceinline__ short f2bf(float x) {
  __hip_bfloat16 h = __float2bfloat16(x);
  return __builtin_bit_cast(short, h);
}

enum { EP_Q = 0, EP_KV = 1, EP_RESID_LN = 2, EP_GELU = 3, EP_RESID = 4 };

// ---------------- weight pack: W[K][N] f32 -> MFMA B-frag order bf16 ---------
template <int K, int N>
__global__ __launch_bounds__(64) void pack_b(const float* __restrict__ W,
                                             short* __restrict__ dst) {
  const int blk = blockIdx.x;  // c*(K/32)+ks
  const int ks = blk % (K / 32), c = blk / (K / 32);
  const int lane = threadIdx.x;
  const int col = c * 16 + (lane & 15);
  const int krow = ks * 32 + (lane >> 4) * 8;
  bf16x8 v;
#pragma unroll
  for (int j = 0; j < 8; ++j) v[j] = f2bf(W[(size_t)(krow + j) * N + col]);
  *(bf16x8*)(dst + ((size_t)blk * 64 + lane) * 8) = v;
}

// ---------------- resolved neighborhood rows: invalid -> TOK -----------------
__global__ __launch_bounds__(256) void idx_kernel(int* __restrict__ gIdx) {
  int w = blockIdx.x;
  int m = threadIdx.x;
  if (m >= 224) return;
  int ww = w & 15, wh = (w >> 4) & 15, wd = w >> 8;
  int t = TOK;  // sentinel row holds bkv projection
  if (m < 216) {
    int lw = m & 1;  int t1 = m >> 1;
    int dk = t1 % 3; int t2 = t1 / 3;
    int lh = t2 & 1; int t3 = t2 >> 1;
    int dj = t3 % 3; int t4 = t3 / 3;
    int ld = t4 & 1; int di = t4 >> 1;
    int nwd = wd + di - 1, nwh = wh + dj - 1, nww = ww + dk - 1;
    int slab = di * 9 + dj * 3 + dk;
    if (nwd >= 0 && nwd <= 15 && nwh >= 0 && nwh <= 15 && nww >= 0 && nww <= 15 && slab != 20) {
      t = ((nwd * 2 + ld) * 32 + (nwh * 2 + lh)) * 32 + (nww * 2 + lw);
    }
  }
  gIdx[w * 224 + m] = t;
}

// write bkv projection into extension rows of kb/vb
__global__ __launch_bounds__(384) void cast_bkv(const float* __restrict__ bkv,
                                                short* __restrict__ kext,
                                                short* __restrict__ vext) {
  int i = threadIdx.x;
  if (i < 192) kext[i] = f2bf(bkv[i]);
  else         vext[i - 192] = f2bf(bkv[i]);
}

// ---------------- bf16 MFMA GEMM with optional fused LN ----------------------
// PROLN: A is f32, LayerNorm(lg,lb) applied in-register before fragging.
// EP_RESID_LN: C0=x1 (f32, acc+bias+resid), C1=LN2(x1) bf16.
template <int EPI, bool PROLN, int K, int NTOT>
__global__ __launch_bounds__(256) void gemm_mfma(const void* __restrict__ Av,
                                                 const short* __restrict__ Bp,
                                                 const float* __restrict__ bias,
                                                 const float* __restrict__ resid,
                                                 const float* __restrict__ lg,
                                                 const float* __restrict__ lb,
                                                 void* __restrict__ C0v,
                                                 void* __restrict__ C1v) {
  const int lane = threadIdx.x & 63;
  const int wv = threadIdx.x >> 6;
  const int lrow = lane & 15, lkg = lane >> 4;
  const int rb = blockIdx.x * 64 + wv * 16;
  const int nb = blockIdx.y * 192;
  const int nb16 = nb >> 4;
  constexpr int KS = K / 32;

  bf16x8 af[KS];
  if constexpr (PROLN) {
    const float* Arow = (const float*)Av + (size_t)(rb + lrow) * K + lkg * 8;
    float v[KS][8];
    float s = 0.f;
#pragma unroll
    for (int ks = 0; ks < KS; ++ks) {
      float4 lo = *(const float4*)(Arow + ks * 32);
      float4 hi = *(const float4*)(Arow + ks * 32 + 4);
      v[ks][0] = lo.x; v[ks][1] = lo.y; v[ks][2] = lo.z; v[ks][3] = lo.w;
      v[ks][4] = hi.x; v[ks][5] = hi.y; v[ks][6] = hi.z; v[ks][7] = hi.w;
#pragma unroll
      for (int j = 0; j < 8; ++j) s += v[ks][j];
    }
    // row channels live in 4 lanes (same lrow, lkg 0..3): xor16 + xor32
    s += __shfl_xor(s, 16); s += __shfl_xor(s, 32);
    float mean = s * (1.f / 192.f);
    float vs = 0.f;
#pragma unroll
    for (int ks = 0; ks < KS; ++ks)
#pragma unroll
      for (int j = 0; j < 8; ++j) { float d = v[ks][j] - mean; vs += d * d; }
    vs += __shfl_xor(vs, 16); vs += __shfl_xor(vs, 32);
    float rstd = rsqrtf(vs * (1.f / 192.f) + 1e-5f);
#pragma unroll
    for (int ks = 0; ks < KS; ++ks)
#pragma unroll
      for (int j = 0; j < 8; ++j) {
        int ch = ks * 32 + lkg * 8 + j;
        af[ks][j] = f2bf((v[ks][j] - mean) * rstd * lg[ch] + lb[ch]);
      }
  } else {
    const short* Arow = (const short*)Av + (size_t)(rb + lrow) * K + lkg * 8;
#pragma unroll
    for (int ks = 0; ks < KS; ++ks) af[ks] = *(const bf16x8*)(Arow + ks * 32);
  }

  f32x4 acc[12];
#pragma unroll
  for (int c = 0; c < 12; ++c) acc[c] = (f32x4){0.f, 0.f, 0.f, 0.f};
#pragma unroll
  for (int ks = 0; ks < KS; ++ks) {
#pragma unroll
    for (int c = 0; c < 12; ++c) {
      bf16x8 bfr = *(const bf16x8*)(Bp + (((size_t)(nb16 + c) * KS + ks) * 64 + lane) * 8);
      acc[c] = __builtin_amdgcn_mfma_f32_16x16x32_bf16(af[ks], bfr, acc[c], 0, 0, 0);
    }
  }

  if constexpr (EPI == EP_RESID_LN) {
    // x1 = acc + bias + resid (f32 out), then row-LN -> bf16 C1
    float vals[12][4];
#pragma unroll
    for (int c = 0; c < 12; ++c) {
      int col = c * 16 + lrow;
      float bia = bias[col];
#pragma unroll
      for (int i = 0; i < 4; ++i) {
        int row = rb + lkg * 4 + i;
        vals[c][i] = acc[c][i] + bia + resid[(size_t)row * 192 + col];
        ((float*)C0v)[(size_t)row * 192 + col] = vals[c][i];
      }
    }
#pragma unroll
    for (int i = 0; i < 4; ++i) {
      int row = rb + lkg * 4 + i;
      float s2 = 0.f;
#pragma unroll
      for (int c = 0; c < 12; ++c) s2 += vals[c][i];
      s2 += __shfl_xor(s2, 1); s2 += __shfl_xor(s2, 2);
      s2 += __shfl_xor(s2, 4); s2 += __shfl_xor(s2, 8);
      float mean = s2 * (1.f / 192.f);
      float vs2 = 0.f;
#pragma unroll
      for (int c = 0; c < 12; ++c) { float d = vals[c][i] - mean; vs2 += d * d; }
      vs2 += __shfl_xor(vs2, 1); vs2 += __shfl_xor(vs2, 2);
      vs2 += __shfl_xor(vs2, 4); vs2 += __shfl_xor(vs2, 8);
      float rstd = rsqrtf(vs2 * (1.f / 192.f) + 1e-5f);
#pragma unroll
      for (int c = 0; c < 12; ++c) {
        int col = c * 16 + lrow;
        ((short*)C1v)[(size_t)row * 192 + col] =
            f2bf((vals[c][i] - mean) * rstd * lg[col] + lb[col]);
      }
    }
  } else {
#pragma unroll
    for (int c = 0; c < 12; ++c) {
      int col = nb + c * 16 + lrow;
      float bia = bias[col];
#pragma unroll
      for (int i = 0; i < 4; ++i) {
        int row = rb + lkg * 4 + i;
        float v = acc[c][i] + bia;
        if constexpr (EPI == EP_Q) {
          ((short*)C0v)[(size_t)row * NTOT + col] = f2bf(v);
        } else if constexpr (EPI == EP_KV) {
          if (col < 192) ((short*)C0v)[(size_t)row * 192 + col] = f2bf(v);
          else           ((short*)C1v)[(size_t)row * 192 + col - 192] = f2bf(v);
        } else if constexpr (EPI == EP_RESID) {
          ((float*)C0v)[(size_t)row * NTOT + col] = v + resid[(size_t)row * NTOT + col];
        } else {  // EP_GELU
          float gg = 0.5f * v * (1.f + erff(v * 0.70710678118654752f));
          ((short*)C0v)[(size_t)row * NTOT + col] = f2bf(gg);
        }
      }
    }
  }
}

// ---------------- Attention: 1 wave per (window, head), barrier-free ---------
// Branch-free gathers via resolved-row gIdx (row TOK = bkv). P->LDS is plain
// b16 scalar stores (no shuffles). PV via ds_read_b64_tr_b16.
__global__ __launch_bounds__(128, 3) void attn_mfma(const short* __restrict__ qbuf,
                                                    const short* __restrict__ kbuf,
                                                    const short* __restrict__ vbuf,
                                                    const int* __restrict__ gIdx,
                                                    short* __restrict__ obuf) {
  __shared__ __align__(16) short VsS[2][224 * 16];
  __shared__ __align__(16) short PsS[2][8 * 232];

  const int tid = threadIdx.x;
  const int wv = tid >> 6;
  const int lane = tid & 63;
  const int lrow = lane & 15, lkg = lane >> 4;

  unsigned bid = blockIdx.x;
  unsigned u = (bid & 7u) * 3072u + (bid >> 3);  // bijective, 24576 blocks
  int w = (int)(u / 6u);
  int h = (int)(u % 6u) * 2 + wv;
  const int ww = w & 15, wh = (w >> 4) & 15, wd = w >> 8;

  short* Vs = VsS[wv];
  short* Ps = PsS[wv];
  const int* gw = gIdx + (size_t)w * 224;

  // index prefetch (batched 4B loads, L2-resident table)
  int ti[14];
#pragma unroll
  for (int T = 0; T < 14; ++T) ti[T] = gw[T * 16 + lrow];
  int mv[14];
#pragma unroll
  for (int k = 0; k < 14; ++k) mv[k] = gw[(lane >> 2) + k * 16];

  // Q fragment direct (bf16x8, 16B)
  bf16x8 qa = (bf16x8)0;
  if (lrow < 8 && lkg < 2) {
    int ldq = lrow >> 2, lhq = (lrow >> 1) & 1, lwq = lrow & 1;
    int tq = ((wd * 2 + ldq) * 32 + (wh * 2 + lhq)) * 32 + (ww * 2 + lwq);
    qa = *(const bf16x8*)(qbuf + (size_t)tq * 192 + h * 16 + lkg * 8);
  }

  // K frags: 14 branch-free gathers issued back-to-back
  bf16x8 kf[14];
#pragma unroll
  for (int T = 0; T < 14; ++T) {
    kf[T] = (bf16x8)0;
    if (lkg < 2)
      kf[T] = *(const bf16x8*)(kbuf + (size_t)ti[T] * 192 + h * 16 + lkg * 8);
  }

  // QK^T
  f32x4 s[14];
  const f32x4 zero4 = {0.f, 0.f, 0.f, 0.f};
#pragma unroll
  for (int T = 0; T < 14; ++T)
    s[T] = __builtin_amdgcn_mfma_f32_16x16x32_bf16(qa, kf[T], zero4, 0, 0, 0);
  if (lrow >= 8) {  // mask padded tokens 216..223
    s[13][0] = -1e30f; s[13][1] = -1e30f; s[13][2] = -1e30f; s[13][3] = -1e30f;
  }

  // V loads issued now; latency hides under softmax + P-pack
  const int q4c = (lane & 3) * 4;
  bf16x4 vv[14];
#pragma unroll
  for (int k = 0; k < 14; ++k)
    vv[k] = *(const bf16x4*)(vbuf + (size_t)mv[k] * 192 + h * 16 + q4c);

  // softmax (in-register, 16-lane column groups), balanced max tree
  float inv[4];
  const float SCL = 0.25f * 1.44269504088896f;
#pragma unroll
  for (int r = 0; r < 4; ++r) {
    float m0 = fmaxf(fmaxf(s[0][r], s[1][r]), s[2][r]);
    float m1 = fmaxf(fmaxf(s[3][r], s[4][r]), s[5][r]);
    float m2 = fmaxf(fmaxf(s[6][r], s[7][r]), s[8][r]);
    float m3 = fmaxf(fmaxf(s[9][r], s[10][r]), s[11][r]);
    float m4 = fmaxf(s[12][r], s[13][r]);
    float mx = fmaxf(fmaxf(fmaxf(m0, m1), fmaxf(m2, m3)), m4);
    mx = fmaxf(mx, __shfl_xor(mx, 1));
    mx = fmaxf(mx, __shfl_xor(mx, 2));
    mx = fmaxf(mx, __shfl_xor(mx, 4));
    mx = fmaxf(mx, __shfl_xor(mx, 8));
    float sum = 0.f;
#pragma unroll
    for (int t = 0; t < 14; ++t) {
      float p = exp2f((s[t][r] - mx) * SCL);
      s[t][r] = p;
      sum += p;
    }
    sum += __shfl_xor(sum, 1);
    sum += __shfl_xor(sum, 2);
    sum += __shfl_xor(sum, 4);
    sum += __shfl_xor(sum, 8);
    inv[r] = 1.f / sum;
  }

  // P -> LDS: plain b16 scalar stores (rows r/r+4 x 16 cols; conflict-benign)
  if (lane < 32) {
    const int rbase = (lane >> 4) * 4;
    short* Pw = Ps + lrow;
#pragma unroll
    for (int r = 0; r < 4; ++r)
#pragma unroll
      for (int t = 0; t < 14; ++t)
        Pw[(rbase + r) * 232 + t * 16] = f2bf(s[t][r]);
  }

  // V -> LDS (token-major [224][16]), linear 8B writes
#pragma unroll
  for (int k = 0; k < 14; ++k)
    *(bf16x4*)(Vs + ((unsigned)lane + (unsigned)k * 64u) * 4u) = vv[k];
  asm volatile("s_waitcnt lgkmcnt(0)" ::: "memory");
  __builtin_amdgcn_sched_barrier(0);

  // PV: tr-reads + P frags, single wait, 7 MFMA
  unsigned vbase = (unsigned)(size_t)((__attribute__((address_space(3))) short*)Vs)
                 + (unsigned)(lkg * 256 + (lrow >> 2) * 32 + (lane & 3) * 8);
  bf16x4 t0[7], t1[7];
#pragma unroll
  for (int T = 0; T < 7; ++T) {
    unsigned a = vbase + (unsigned)(T * 1024);
    asm volatile("ds_read_b64_tr_b16 %0, %1" : "=v"(t0[T]) : "v"(a));
    asm volatile("ds_read_b64_tr_b16 %0, %1 offset:128" : "=v"(t1[T]) : "v"(a));
  }
  bf16x8 pa[7];
#pragma unroll
  for (int T = 0; T < 7; ++T) {
    pa[T] = (bf16x8)0;
    if (lrow < 8) pa[T] = *(const bf16x8*)(Ps + lrow * 232 + T * 32 + lkg * 8);
  }
  asm volatile("s_waitcnt lgkmcnt(0)" ::: "memory");
  __builtin_amdgcn_sched_barrier(0);
  f32x4 o = {0.f, 0.f, 0.f, 0.f};
#pragma unroll
  for (int T = 0; T < 7; ++T) {
    bf16x8 vf = __builtin_shufflevector(t0[T], t1[T], 0, 1, 2, 3, 4, 5, 6, 7);
    o = __builtin_amdgcn_mfma_f32_16x16x32_bf16(pa[T], vf, o, 0, 0, 0);
  }

  // store O (bf16, normalized)
  if (lane < 32) {
#pragma unroll
    for (int r = 0; r < 4; ++r) {
      int n = (lane >> 4) * 4 + r;
      int ldq = n >> 2, lhq = (n >> 1) & 1, lwq = n & 1;
      int tq = ((wd * 2 + ldq) * 32 + (wh * 2 + lhq)) * 32 + (ww * 2 + lwq);
      obuf[(size_t)tq * 192 + h * 16 + lrow] = f2bf(o[r] * inv[r]);
    }
  }
}

extern "C" void kernel_launch(void* const* d_in, const int* in_sizes, int n_in,
                              void* d_out, int out_size, void* d_ws, size_t ws_size,
                              hipStream_t stream) {
  const float* x   = (const float*)d_in[0];
  const float* xa  = (const float*)d_in[1];
  const float* n1g = (const float*)d_in[2];
  const float* n1b = (const float*)d_in[3];
  const float* n2g = (const float*)d_in[4];
  const float* n2b = (const float*)d_in[5];
  const float* Wq  = (const float*)d_in[6];
  const float* bq  = (const float*)d_in[7];
  const float* Wkv = (const float*)d_in[8];
  const float* bkv = (const float*)d_in[9];
  const float* Wp  = (const float*)d_in[10];
  const float* bp  = (const float*)d_in[11];
  const float* W1  = (const float*)d_in[12];
  const float* b1  = (const float*)d_in[13];
  const float* W2  = (const float*)d_in[14];
  const float* b2  = (const float*)d_in[15];

  char* wsb = (char*)d_ws;
  const size_t BB = (size_t)TOK * 192 * 2;  // 12.58 MB bf16 token buffer
  short* attn_o = (short*)(wsb + 0 * BB);
  short* xn2    = (short*)(wsb + 1 * BB);               // LN2 out (bf16)
  short* qb     = (short*)(wsb + 2 * BB);               // Q; later hmlp spans qb..kb
  short* kb     = (short*)(wsb + 3 * BB);               // K + ext row TOK
  short* vb     = (short*)(wsb + 4 * BB + 4096);        // V + ext row TOK
  float* x1     = (float*)(wsb + 5 * BB + 8192);        // f32 [TOK][192] (2*BB)
  char* p = wsb + 7 * BB + 16384;
  int* gIdx = (int*)p;            p += (size_t)NWIN * 224 * 4;
  short* wq_p  = (short*)p;       p += 192 * 192 * 2;
  short* wkv_p = (short*)p;       p += 192 * 384 * 2;
  short* wp_p  = (short*)p;       p += 192 * 192 * 2;
  short* w1_p  = (short*)p;       p += 192 * 384 * 2;
  short* w2_p  = (short*)p;       p += 384 * 192 * 2;

  short* hmlp = qb;  // [TOK][384] bf16 spans qb(BB) + kb region

  idx_kernel<<<NWIN, 256, 0, stream>>>(gIdx);
  cast_bkv<<<1, 384, 0, stream>>>(bkv, kb + (size_t)TOK * 192, vb + (size_t)TOK * 192);
  pack_b<192, 192><<<12 * 6, 64, 0, stream>>>(Wq, wq_p);
  pack_b<192, 384><<<24 * 6, 64, 0, stream>>>(Wkv, wkv_p);
  pack_b<192, 192><<<12 * 6, 64, 0, stream>>>(Wp, wp_p);
  pack_b<192, 384><<<24 * 6, 64, 0, stream>>>(W1, w1_p);
  pack_b<384, 192><<<12 * 12, 64, 0, stream>>>(W2, w2_p);

  // Q = LN1(x)@Wq+bq ; K,V = LN1(xa)@Wkv+bkv  (LN fused as prologue)
  gemm_mfma<EP_Q, true, 192, 192><<<dim3(512, 1), 256, 0, stream>>>(
      x, wq_p, bq, nullptr, n1g, n1b, qb, nullptr);
  gemm_mfma<EP_KV, true, 192, 384><<<dim3(512, 2), 256, 0, stream>>>(
      xa, wkv_p, bkv, nullptr, n1g, n1b, kb, vb);

  attn_mfma<<<NWIN * 6, 128, 0, stream>>>(qb, kb, vb, gIdx, attn_o);

  // x1 = x + attn_o@Wp+bp ; xn2 = LN2(x1)  (LN fused as epilogue)
  gemm_mfma<EP_RESID_LN, false, 192, 192><<<dim3(512, 1), 256, 0, stream>>>(
      attn_o, wp_p, bp, x, n2g, n2b, x1, xn2);

  gemm_mfma<EP_GELU, false, 192, 384><<<dim3(512, 2), 256, 0, stream>>>(
      xn2, w1_p, b1, nullptr, nullptr, nullptr, hmlp, nullptr);
  gemm_mfma<EP_RESID, false, 384, 192><<<dim3(512, 1), 256, 0, stream>>>(
      hmlp, w2_p, b2, x1, nullptr, nullptr, (float*)d_out, nullptr);
}

// Round 10
// 254.439 us; speedup vs baseline: 3.3057x; 1.0352x over previous
//
#include <hip/hip_runtime.h>
#include <hip/hip_bf16.h>
#include <math.h>

// CrossTransformerBlock3D: D=H=W=32, DIM=192, HEADS=12, HD=16, WS=2x2x2
// bf16-MFMA everywhere. LN1 fused into Q/KV GEMM prologue, LN2 into P-GEMM
// epilogue. Q pre-scaled by 0.25*log2e so attn softmax is exp2(s) directly
// (no max pass -- scores |s|<~1, overflow needs |s|>350). MT=2 GEMMs halve
// B-panel L2 traffic. Single fused prep kernel (idx+cast+5 weight packs).

#define TOK 32768
#define NWIN 4096

typedef float f32x4 __attribute__((ext_vector_type(4)));
typedef short bf16x8 __attribute__((ext_vector_type(8)));
typedef short bf16x4 __attribute__((ext_vector_type(4)));

static __device__ __forceinline__ short f2bf(float x) {
  __hip_bfloat16 h = __float2bfloat16(x);
  return __builtin_bit_cast(short, h);
}

enum { EP_Q = 0, EP_KV = 1, EP_RESID_LN = 2, EP_GELU = 3, EP_RESID = 4 };

// ---------------- fused prep: weight packs + neighborhood idx + bkv cast -----
// pack: dst[((c*(K/32)+ks)*64+lane)*8+j] = bf16(W[ks*32+(lane>>4)*8+j][c*16+(lane&15)])
static __device__ __forceinline__ void pack_one(const float* __restrict__ W,
                                                short* __restrict__ dst,
                                                int K, int N, int blk, int lane) {
  int KS = K / 32;
  int ks = blk % KS, c = blk / KS;
  int col = c * 16 + (lane & 15);
  int krow = ks * 32 + (lane >> 4) * 8;
  bf16x8 v;
#pragma unroll
  for (int j = 0; j < 8; ++j) v[j] = f2bf(W[(size_t)(krow + j) * N + col]);
  *(bf16x8*)(dst + ((size_t)blk * 64 + lane) * 8) = v;
}

// pack blocks: wq 72 | wkv 144 | wp 72 | w1 144 | w2 144 = 576 -> 144 merged
__global__ __launch_bounds__(256) void prep_kernel(
    const float* __restrict__ Wq, const float* __restrict__ Wkv,
    const float* __restrict__ Wp, const float* __restrict__ W1,
    const float* __restrict__ W2, const float* __restrict__ bkv,
    short* __restrict__ wq_p, short* __restrict__ wkv_p, short* __restrict__ wp_p,
    short* __restrict__ w1_p, short* __restrict__ w2_p,
    short* __restrict__ kext, short* __restrict__ vext,
    int* __restrict__ gIdx) {
  int bid = blockIdx.x;
  int tid = threadIdx.x;
  if (bid < 144) {  // 4 pack-units per block
    int pb = bid * 4 + (tid >> 6);
    int lane = tid & 63;
    if (pb < 72)        pack_one(Wq,  wq_p,  192, 192, pb,       lane);
    else if (pb < 216)  pack_one(Wkv, wkv_p, 192, 384, pb - 72,  lane);
    else if (pb < 288)  pack_one(Wp,  wp_p,  192, 192, pb - 216, lane);
    else if (pb < 432)  pack_one(W1,  w1_p,  192, 384, pb - 288, lane);
    else                pack_one(W2,  w2_p,  384, 192, pb - 432, lane);
  } else if (bid < 144 + NWIN) {  // neighborhood idx, resolved rows
    int w = bid - 144;
    int m = tid;
    if (m >= 224) return;
    int ww = w & 15, wh = (w >> 4) & 15, wd = w >> 8;
    int t = TOK;  // sentinel row = bkv projection
    if (m < 216) {
      int lw = m & 1;  int t1 = m >> 1;
      int dk = t1 % 3; int t2 = t1 / 3;
      int lh = t2 & 1; int t3 = t2 >> 1;
      int dj = t3 % 3; int t4 = t3 / 3;
      int ld = t4 & 1; int di = t4 >> 1;
      int nwd = wd + di - 1, nwh = wh + dj - 1, nww = ww + dk - 1;
      int slab = di * 9 + dj * 3 + dk;
      if (nwd >= 0 && nwd <= 15 && nwh >= 0 && nwh <= 15 && nww >= 0 && nww <= 15 && slab != 20) {
        t = ((nwd * 2 + ld) * 32 + (nwh * 2 + lh)) * 32 + (nww * 2 + lw);
      }
    }
    gIdx[w * 224 + m] = t;
  } else {  // bkv extension rows
    if (tid < 192)      kext[tid] = f2bf(bkv[tid]);
    else if (tid < 384) vext[tid - 192] = f2bf(bkv[tid]);
  }
}

// ---------------- bf16 MFMA GEMM (MT row-tiles/wave, optional fused LN) ------
// PROLN: A f32, LayerNorm(lg,lb) in-register before fragging (MT=1 only).
// EP_Q: C0 = bf16((acc+bias) * 0.25*log2e)  [pre-scaled Q for exp2 softmax]
// EP_RESID_LN: C0 = x1 f32 (acc+bias+resid), C1 = bf16 LN2(x1).
template <int EPI, bool PROLN, int MT, int K, int NTOT>
__global__ __launch_bounds__(256, 1) void gemm_mfma(const void* __restrict__ Av,
                                                    const short* __restrict__ Bp,
                                                    const float* __restrict__ bias,
                                                    const float* __restrict__ resid,
                                                    const float* __restrict__ lg,
                                                    const float* __restrict__ lb,
                                                    void* __restrict__ C0v,
                                                    void* __restrict__ C1v) {
  const int lane = threadIdx.x & 63;
  const int wv = threadIdx.x >> 6;
  const int lrow = lane & 15, lkg = lane >> 4;
  const int wrb = blockIdx.x * (64 * MT) + wv * (16 * MT);
  const int nb = blockIdx.y * 192;
  const int nb16 = nb >> 4;
  constexpr int KS = K / 32;

  f32x4 acc[MT][12];
#pragma unroll
  for (int mt = 0; mt < MT; ++mt)
#pragma unroll
    for (int c = 0; c < 12; ++c) acc[mt][c] = (f32x4){0.f, 0.f, 0.f, 0.f};

  if constexpr (PROLN) {
    static_assert(MT == 1);
    const float* Arow = (const float*)Av + (size_t)(wrb + lrow) * K + lkg * 8;
    float v[KS][8];
    float s = 0.f;
#pragma unroll
    for (int ks = 0; ks < KS; ++ks) {
      float4 lo = *(const float4*)(Arow + ks * 32);
      float4 hi = *(const float4*)(Arow + ks * 32 + 4);
      v[ks][0] = lo.x; v[ks][1] = lo.y; v[ks][2] = lo.z; v[ks][3] = lo.w;
      v[ks][4] = hi.x; v[ks][5] = hi.y; v[ks][6] = hi.z; v[ks][7] = hi.w;
#pragma unroll
      for (int j = 0; j < 8; ++j) s += v[ks][j];
    }
    s += __shfl_xor(s, 16); s += __shfl_xor(s, 32);
    float mean = s * (1.f / 192.f);
    float vs = 0.f;
#pragma unroll
    for (int ks = 0; ks < KS; ++ks)
#pragma unroll
      for (int j = 0; j < 8; ++j) { float d = v[ks][j] - mean; vs += d * d; }
    vs += __shfl_xor(vs, 16); vs += __shfl_xor(vs, 32);
    float rstd = rsqrtf(vs * (1.f / 192.f) + 1e-5f);
    bf16x8 af[KS];
#pragma unroll
    for (int ks = 0; ks < KS; ++ks)
#pragma unroll
      for (int j = 0; j < 8; ++j) {
        int ch = ks * 32 + lkg * 8 + j;
        af[ks][j] = f2bf((v[ks][j] - mean) * rstd * lg[ch] + lb[ch]);
      }
#pragma unroll
    for (int ks = 0; ks < KS; ++ks)
#pragma unroll
      for (int c = 0; c < 12; ++c) {
        bf16x8 bfr = *(const bf16x8*)(Bp + (((size_t)(nb16 + c) * KS + ks) * 64 + lane) * 8);
        acc[0][c] = __builtin_amdgcn_mfma_f32_16x16x32_bf16(af[ks], bfr, acc[0][c], 0, 0, 0);
      }
  } else {
    const short* Abase = (const short*)Av + (size_t)(wrb + lrow) * K + lkg * 8;
#pragma unroll
    for (int ks = 0; ks < KS; ++ks) {
      bf16x8 af[MT];
#pragma unroll
      for (int mt = 0; mt < MT; ++mt)
        af[mt] = *(const bf16x8*)(Abase + (size_t)mt * 16 * K + ks * 32);
#pragma unroll
      for (int c = 0; c < 12; ++c) {
        bf16x8 bfr = *(const bf16x8*)(Bp + (((size_t)(nb16 + c) * KS + ks) * 64 + lane) * 8);
#pragma unroll
        for (int mt = 0; mt < MT; ++mt)
          acc[mt][c] = __builtin_amdgcn_mfma_f32_16x16x32_bf16(af[mt], bfr, acc[mt][c], 0, 0, 0);
      }
    }
  }

  if constexpr (EPI == EP_RESID_LN) {
#pragma unroll
    for (int mt = 0; mt < MT; ++mt) {
      // x1 = acc + bias + resid (f32), in-place in acc
#pragma unroll
      for (int c = 0; c < 12; ++c) {
        int col = c * 16 + lrow;
        float bia = bias[col];
#pragma unroll
        for (int i = 0; i < 4; ++i) {
          int row = wrb + mt * 16 + lkg * 4 + i;
          acc[mt][c][i] += bia + resid[(size_t)row * 192 + col];
          ((float*)C0v)[(size_t)row * 192 + col] = acc[mt][c][i];
        }
      }
#pragma unroll
      for (int i = 0; i < 4; ++i) {
        int row = wrb + mt * 16 + lkg * 4 + i;
        float s2 = 0.f;
#pragma unroll
        for (int c = 0; c < 12; ++c) s2 += acc[mt][c][i];
        s2 += __shfl_xor(s2, 1); s2 += __shfl_xor(s2, 2);
        s2 += __shfl_xor(s2, 4); s2 += __shfl_xor(s2, 8);
        float mean = s2 * (1.f / 192.f);
        float vs2 = 0.f;
#pragma unroll
        for (int c = 0; c < 12; ++c) { float d = acc[mt][c][i] - mean; vs2 += d * d; }
        vs2 += __shfl_xor(vs2, 1); vs2 += __shfl_xor(vs2, 2);
        vs2 += __shfl_xor(vs2, 4); vs2 += __shfl_xor(vs2, 8);
        float rstd = rsqrtf(vs2 * (1.f / 192.f) + 1e-5f);
#pragma unroll
        for (int c = 0; c < 12; ++c) {
          int col = c * 16 + lrow;
          ((short*)C1v)[(size_t)row * 192 + col] =
              f2bf((acc[mt][c][i] - mean) * rstd * lg[col] + lb[col]);
        }
      }
    }
  } else {
#pragma unroll
    for (int mt = 0; mt < MT; ++mt)
#pragma unroll
      for (int c = 0; c < 12; ++c) {
        int col = nb + c * 16 + lrow;
        float bia = bias[col];
#pragma unroll
        for (int i = 0; i < 4; ++i) {
          int row = wrb + mt * 16 + lkg * 4 + i;
          float v = acc[mt][c][i] + bia;
          if constexpr (EPI == EP_Q) {
            ((short*)C0v)[(size_t)row * NTOT + col] = f2bf(v * 0.36067376022224085f);
          } else if constexpr (EPI == EP_KV) {
            if (col < 192) ((short*)C0v)[(size_t)row * 192 + col] = f2bf(v);
            else           ((short*)C1v)[(size_t)row * 192 + col - 192] = f2bf(v);
          } else if constexpr (EPI == EP_RESID) {
            ((float*)C0v)[(size_t)row * NTOT + col] = v + resid[(size_t)row * NTOT + col];
          } else {  // EP_GELU
            float gg = 0.5f * v * (1.f + erff(v * 0.70710678118654752f));
            ((short*)C0v)[(size_t)row * NTOT + col] = f2bf(gg);
          }
        }
      }
  }
}

// ---------------- Attention: 1 wave per (window, head), barrier-free ---------
// Q pre-scaled: softmax = exp2(s) directly, no max pass (|s| << overflow).
__global__ __launch_bounds__(128, 3) void attn_mfma(const short* __restrict__ qbuf,
                                                    const short* __restrict__ kbuf,
                                                    const short* __restrict__ vbuf,
                                                    const int* __restrict__ gIdx,
                                                    short* __restrict__ obuf) {
  __shared__ __align__(16) short VsS[2][224 * 16];
  __shared__ __align__(16) short PsS[2][8 * 232];

  const int tid = threadIdx.x;
  const int wv = tid >> 6;
  const int lane = tid & 63;
  const int lrow = lane & 15, lkg = lane >> 4;

  unsigned bid = blockIdx.x;
  unsigned u = (bid & 7u) * 3072u + (bid >> 3);  // bijective, 24576 blocks
  int w = (int)(u / 6u);
  int h = (int)(u % 6u) * 2 + wv;
  const int ww = w & 15, wh = (w >> 4) & 15, wd = w >> 8;

  short* Vs = VsS[wv];
  short* Ps = PsS[wv];
  const int* gw = gIdx + (size_t)w * 224;

  // index prefetch (batched 4B loads, L2-resident table)
  int ti[14];
#pragma unroll
  for (int T = 0; T < 14; ++T) ti[T] = gw[T * 16 + lrow];
  int mv[14];
#pragma unroll
  for (int k = 0; k < 14; ++k) mv[k] = gw[(lane >> 2) + k * 16];

  // Q fragment direct (bf16x8, 16B; pre-scaled by 0.25*log2e)
  bf16x8 qa = (bf16x8)0;
  if (lrow < 8 && lkg < 2) {
    int ldq = lrow >> 2, lhq = (lrow >> 1) & 1, lwq = lrow & 1;
    int tq = ((wd * 2 + ldq) * 32 + (wh * 2 + lhq)) * 32 + (ww * 2 + lwq);
    qa = *(const bf16x8*)(qbuf + (size_t)tq * 192 + h * 16 + lkg * 8);
  }

  // K frags: 14 branch-free gathers issued back-to-back
  bf16x8 kf[14];
#pragma unroll
  for (int T = 0; T < 14; ++T) {
    kf[T] = (bf16x8)0;
    if (lkg < 2)
      kf[T] = *(const bf16x8*)(kbuf + (size_t)ti[T] * 192 + h * 16 + lkg * 8);
  }

  // QK^T
  f32x4 s[14];
  const f32x4 zero4 = {0.f, 0.f, 0.f, 0.f};
#pragma unroll
  for (int T = 0; T < 14; ++T)
    s[T] = __builtin_amdgcn_mfma_f32_16x16x32_bf16(qa, kf[T], zero4, 0, 0, 0);
  if (lrow >= 8) {  // mask padded tokens 216..223 -> exp2(-1e30)=0
    s[13][0] = -1e30f; s[13][1] = -1e30f; s[13][2] = -1e30f; s[13][3] = -1e30f;
  }

  // V loads issued now; latency hides under softmax + P-pack
  const int q4c = (lane & 3) * 4;
  bf16x4 vv[14];
#pragma unroll
  for (int k = 0; k < 14; ++k)
    vv[k] = *(const bf16x4*)(vbuf + (size_t)mv[k] * 192 + h * 16 + q4c);

  // softmax: p = exp2(s) (Q pre-scaled), sum-reduce over 16-lane groups
  float inv[4];
#pragma unroll
  for (int r = 0; r < 4; ++r) {
    float sum = 0.f;
#pragma unroll
    for (int t = 0; t < 14; ++t) {
      float p = exp2f(s[t][r]);
      s[t][r] = p;
      sum += p;
    }
    sum += __shfl_xor(sum, 1);
    sum += __shfl_xor(sum, 2);
    sum += __shfl_xor(sum, 4);
    sum += __shfl_xor(sum, 8);
    inv[r] = 1.f / sum;
  }

  // P -> LDS: plain b16 scalar stores
  if (lane < 32) {
    const int rbase = (lane >> 4) * 4;
    short* Pw = Ps + lrow;
#pragma unroll
    for (int r = 0; r < 4; ++r)
#pragma unroll
      for (int t = 0; t < 14; ++t)
        Pw[(rbase + r) * 232 + t * 16] = f2bf(s[t][r]);
  }

  // V -> LDS (token-major [224][16]), linear 8B writes
#pragma unroll
  for (int k = 0; k < 14; ++k)
    *(bf16x4*)(Vs + ((unsigned)lane + (unsigned)k * 64u) * 4u) = vv[k];
  asm volatile("s_waitcnt lgkmcnt(0)" ::: "memory");
  __builtin_amdgcn_sched_barrier(0);

  // PV: tr-reads + P frags, single wait, 7 MFMA
  unsigned vbase = (unsigned)(size_t)((__attribute__((address_space(3))) short*)Vs)
                 + (unsigned)(lkg * 256 + (lrow >> 2) * 32 + (lane & 3) * 8);
  bf16x4 t0[7], t1[7];
#pragma unroll
  for (int T = 0; T < 7; ++T) {
    unsigned a = vbase + (unsigned)(T * 1024);
    asm volatile("ds_read_b64_tr_b16 %0, %1" : "=v"(t0[T]) : "v"(a));
    asm volatile("ds_read_b64_tr_b16 %0, %1 offset:128" : "=v"(t1[T]) : "v"(a));
  }
  bf16x8 pa[7];
#pragma unroll
  for (int T = 0; T < 7; ++T) {
    pa[T] = (bf16x8)0;
    if (lrow < 8) pa[T] = *(const bf16x8*)(Ps + lrow * 232 + T * 32 + lkg * 8);
  }
  asm volatile("s_waitcnt lgkmcnt(0)" ::: "memory");
  __builtin_amdgcn_sched_barrier(0);
  f32x4 o = {0.f, 0.f, 0.f, 0.f};
#pragma unroll
  for (int T = 0; T < 7; ++T) {
    bf16x8 vf = __builtin_shufflevector(t0[T], t1[T], 0, 1, 2, 3, 4, 5, 6, 7);
    o = __builtin_amdgcn_mfma_f32_16x16x32_bf16(pa[T], vf, o, 0, 0, 0);
  }

  // store O (bf16, normalized)
  if (lane < 32) {
#pragma unroll
    for (int r = 0; r < 4; ++r) {
      int n = (lane >> 4) * 4 + r;
      int ldq = n >> 2, lhq = (n >> 1) & 1, lwq = n & 1;
      int tq = ((wd * 2 + ldq) * 32 + (wh * 2 + lhq)) * 32 + (ww * 2 + lwq);
      obuf[(size_t)tq * 192 + h * 16 + lrow] = f2bf(o[r] * inv[r]);
    }
  }
}

extern "C" void kernel_launch(void* const* d_in, const int* in_sizes, int n_in,
                              void* d_out, int out_size, void* d_ws, size_t ws_size,
                              hipStream_t stream) {
  const float* x   = (const float*)d_in[0];
  const float* xa  = (const float*)d_in[1];
  const float* n1g = (const float*)d_in[2];
  const float* n1b = (const float*)d_in[3];
  const float* n2g = (const float*)d_in[4];
  const float* n2b = (const float*)d_in[5];
  const float* Wq  = (const float*)d_in[6];
  const float* bq  = (const float*)d_in[7];
  const float* Wkv = (const float*)d_in[8];
  const float* bkv = (const float*)d_in[9];
  const float* Wp  = (const float*)d_in[10];
  const float* bp  = (const float*)d_in[11];
  const float* W1  = (const float*)d_in[12];
  const float* b1  = (const float*)d_in[13];
  const float* W2  = (const float*)d_in[14];
  const float* b2  = (const float*)d_in[15];

  char* wsb = (char*)d_ws;
  const size_t BB = (size_t)TOK * 192 * 2;  // 12.58 MB bf16 token buffer
  short* attn_o = (short*)(wsb + 0 * BB);
  short* xn2    = (short*)(wsb + 1 * BB);               // LN2 out (bf16)
  short* qb     = (short*)(wsb + 2 * BB);               // Q; later hmlp spans qb..kb
  short* kb     = (short*)(wsb + 3 * BB);               // K + ext row TOK
  short* vb     = (short*)(wsb + 4 * BB + 4096);        // V + ext row TOK
  float* x1     = (float*)(wsb + 5 * BB + 8192);        // f32 [TOK][192] (2*BB)
  char* p = wsb + 7 * BB + 16384;
  int* gIdx = (int*)p;            p += (size_t)NWIN * 224 * 4;
  short* wq_p  = (short*)p;       p += 192 * 192 * 2;
  short* wkv_p = (short*)p;       p += 192 * 384 * 2;
  short* wp_p  = (short*)p;       p += 192 * 192 * 2;
  short* w1_p  = (short*)p;       p += 192 * 384 * 2;
  short* w2_p  = (short*)p;       p += 384 * 192 * 2;

  short* hmlp = qb;  // [TOK][384] bf16 spans qb(BB) + kb region

  prep_kernel<<<144 + NWIN + 1, 256, 0, stream>>>(
      Wq, Wkv, Wp, W1, W2, bkv, wq_p, wkv_p, wp_p, w1_p, w2_p,
      kb + (size_t)TOK * 192, vb + (size_t)TOK * 192, gIdx);

  // Q = (LN1(x)@Wq+bq)*0.25*log2e ; K,V = LN1(xa)@Wkv+bkv
  gemm_mfma<EP_Q, true, 1, 192, 192><<<dim3(512, 1), 256, 0, stream>>>(
      x, wq_p, bq, nullptr, n1g, n1b, qb, nullptr);
  gemm_mfma<EP_KV, true, 1, 192, 384><<<dim3(512, 2), 256, 0, stream>>>(
      xa, wkv_p, bkv, nullptr, n1g, n1b, kb, vb);

  attn_mfma<<<NWIN * 6, 128, 0, stream>>>(qb, kb, vb, gIdx, attn_o);

  // x1 = x + attn_o@Wp+bp ; xn2 = LN2(x1)
  gemm_mfma<EP_RESID_LN, false, 2, 192, 192><<<dim3(256, 1), 256, 0, stream>>>(
      attn_o, wp_p, bp, x, n2g, n2b, x1, xn2);

  gemm_mfma<EP_GELU, false, 2, 192, 384><<<dim3(256, 2), 256, 0, stream>>>(
      xn2, w1_p, b1, nullptr, nullptr, nullptr, hmlp, nullptr);
  gemm_mfma<EP_RESID, false, 2, 384, 192><<<dim3(256, 1), 256, 0, stream>>>(
      hmlp, w2_p, b2, x1, nullptr, nullptr, (float*)d_out, nullptr);
}

// Round 11
// 186.147 us; speedup vs baseline: 4.5185x; 1.3669x over previous
//
#include <hip/hip_runtime.h>
#include <hip/hip_bf16.h>
#include <math.h>

// CrossTransformerBlock3D: D=H=W=32, DIM=192, HEADS=12, HD=16, WS=2x2x2
// bf16-MFMA everywhere. LN1 fused into Q/KV GEMM prologue, LN2 into P-GEMM
// epilogue. Q pre-scaled by 0.25*log2e so attn softmax is exp2(s) directly.
// GEMM: 72KB B-panel staged to LDS via global_load_lds, ds_read_b128 frags,
// 2 blocks/CU (8 waves/CU) -- fixes r10's 1-wave/SIMD L2-latency serialization.

#define TOK 32768
#define NWIN 4096

typedef float f32x4 __attribute__((ext_vector_type(4)));
typedef short bf16x8 __attribute__((ext_vector_type(8)));
typedef short bf16x4 __attribute__((ext_vector_type(4)));

static __device__ __forceinline__ short f2bf(float x) {
  __hip_bfloat16 h = __float2bfloat16(x);
  return __builtin_bit_cast(short, h);
}

enum { EP_Q = 0, EP_KV = 1, EP_RESID_LN = 2, EP_GELU = 3, EP_RESID = 4 };

// ---------------- fused prep: weight packs + neighborhood idx + bkv cast -----
static __device__ __forceinline__ void pack_one(const float* __restrict__ W,
                                                short* __restrict__ dst,
                                                int K, int N, int blk, int lane) {
  int KS = K / 32;
  int ks = blk % KS, c = blk / KS;
  int col = c * 16 + (lane & 15);
  int krow = ks * 32 + (lane >> 4) * 8;
  bf16x8 v;
#pragma unroll
  for (int j = 0; j < 8; ++j) v[j] = f2bf(W[(size_t)(krow + j) * N + col]);
  *(bf16x8*)(dst + ((size_t)blk * 64 + lane) * 8) = v;
}

__global__ __launch_bounds__(256) void prep_kernel(
    const float* __restrict__ Wq, const float* __restrict__ Wkv,
    const float* __restrict__ Wp, const float* __restrict__ W1,
    const float* __restrict__ W2, const float* __restrict__ bkv,
    short* __restrict__ wq_p, short* __restrict__ wkv_p, short* __restrict__ wp_p,
    short* __restrict__ w1_p, short* __restrict__ w2_p,
    short* __restrict__ kext, short* __restrict__ vext,
    int* __restrict__ gIdx) {
  int bid = blockIdx.x;
  int tid = threadIdx.x;
  if (bid < 144) {  // 4 pack-units per block
    int pb = bid * 4 + (tid >> 6);
    int lane = tid & 63;
    if (pb < 72)        pack_one(Wq,  wq_p,  192, 192, pb,       lane);
    else if (pb < 216)  pack_one(Wkv, wkv_p, 192, 384, pb - 72,  lane);
    else if (pb < 288)  pack_one(Wp,  wp_p,  192, 192, pb - 216, lane);
    else if (pb < 432)  pack_one(W1,  w1_p,  192, 384, pb - 288, lane);
    else                pack_one(W2,  w2_p,  384, 192, pb - 432, lane);
  } else if (bid < 144 + NWIN) {  // neighborhood idx, resolved rows
    int w = bid - 144;
    int m = tid;
    if (m >= 224) return;
    int ww = w & 15, wh = (w >> 4) & 15, wd = w >> 8;
    int t = TOK;  // sentinel row = bkv projection
    if (m < 216) {
      int lw = m & 1;  int t1 = m >> 1;
      int dk = t1 % 3; int t2 = t1 / 3;
      int lh = t2 & 1; int t3 = t2 >> 1;
      int dj = t3 % 3; int t4 = t3 / 3;
      int ld = t4 & 1; int di = t4 >> 1;
      int nwd = wd + di - 1, nwh = wh + dj - 1, nww = ww + dk - 1;
      int slab = di * 9 + dj * 3 + dk;
      if (nwd >= 0 && nwd <= 15 && nwh >= 0 && nwh <= 15 && nww >= 0 && nww <= 15 && slab != 20) {
        t = ((nwd * 2 + ld) * 32 + (nwh * 2 + lh) ) * 32 + (nww * 2 + lw);
      }
    }
    gIdx[w * 224 + m] = t;
  } else {  // bkv extension rows
    if (tid < 192)      kext[tid] = f2bf(bkv[tid]);
    else if (tid < 384) vext[tid - 192] = f2bf(bkv[tid]);
  }
}

// ---------------- bf16 MFMA GEMM, LDS-staged B-panel -------------------------
// Block: 256 thr = 4 waves x 16 rows = 64 rows; CT col-tiles (16 cols each).
// B-panel CT*(K/32) = 72 chunks x 1KB staged via global_load_lds once.
// PROLN: A f32, LayerNorm(lg,lb) in-register before fragging.
// EP_Q: C0 = bf16((acc+bias)*0.25*log2e). EP_RESID_LN: C0=x1 f32, C1=LN2 bf16.
template <int EPI, bool PROLN, int CT, int K, int NTOT>
__global__ __launch_bounds__(256, 2) void gemm_mfma(const void* __restrict__ Av,
                                                    const short* __restrict__ Bp,
                                                    const float* __restrict__ bias,
                                                    const float* __restrict__ resid,
                                                    const float* __restrict__ lg,
                                                    const float* __restrict__ lb,
                                                    void* __restrict__ C0v,
                                                    void* __restrict__ C1v) {
  constexpr int KS = K / 32;
  constexpr int CHUNKS = CT * KS;  // 1KB each
  static_assert(CHUNKS == 72);
  __shared__ __align__(16) short Bls[CHUNKS * 512];

  const int lane = threadIdx.x & 63;
  const int wv = threadIdx.x >> 6;
  const int lrow = lane & 15, lkg = lane >> 4;
  const int rb = blockIdx.x * 64 + wv * 16;
  const int nb = blockIdx.y * (CT * 16);
  const int nb16 = blockIdx.y * CT;

  // ---- stage B-panel: 18 x global_load_lds(16B) per wave, linear dest
  {
    const short* bsrc = Bp + (size_t)nb16 * KS * 512;
#pragma unroll
    for (int i = 0; i < 18; ++i) {
      int ch = wv * 18 + i;
      __builtin_amdgcn_global_load_lds(
          (const __attribute__((address_space(1))) void*)(bsrc + (size_t)ch * 512 + lane * 8),
          (__attribute__((address_space(3))) void*)(Bls + ch * 512), 16, 0, 0);
    }
  }

  // ---- A fragments (global loads fly during staging; barrier drains both)
  bf16x8 af[KS];
  if constexpr (PROLN) {
    const float* Arow = (const float*)Av + (size_t)(rb + lrow) * K + lkg * 8;
    float v[KS][8];
    float s = 0.f;
#pragma unroll
    for (int ks = 0; ks < KS; ++ks) {
      float4 lo = *(const float4*)(Arow + ks * 32);
      float4 hi = *(const float4*)(Arow + ks * 32 + 4);
      v[ks][0] = lo.x; v[ks][1] = lo.y; v[ks][2] = lo.z; v[ks][3] = lo.w;
      v[ks][4] = hi.x; v[ks][5] = hi.y; v[ks][6] = hi.z; v[ks][7] = hi.w;
#pragma unroll
      for (int j = 0; j < 8; ++j) s += v[ks][j];
    }
    s += __shfl_xor(s, 16); s += __shfl_xor(s, 32);
    float mean = s * (1.f / 192.f);
    float vs = 0.f;
#pragma unroll
    for (int ks = 0; ks < KS; ++ks)
#pragma unroll
      for (int j = 0; j < 8; ++j) { float d = v[ks][j] - mean; vs += d * d; }
    vs += __shfl_xor(vs, 16); vs += __shfl_xor(vs, 32);
    float rstd = rsqrtf(vs * (1.f / 192.f) + 1e-5f);
#pragma unroll
    for (int ks = 0; ks < KS; ++ks)
#pragma unroll
      for (int j = 0; j < 8; ++j) {
        int ch = ks * 32 + lkg * 8 + j;
        af[ks][j] = f2bf((v[ks][j] - mean) * rstd * lg[ch] + lb[ch]);
      }
  } else {
    const short* Arow = (const short*)Av + (size_t)(rb + lrow) * K + lkg * 8;
#pragma unroll
    for (int ks = 0; ks < KS; ++ks) af[ks] = *(const bf16x8*)(Arow + ks * 32);
  }

  __syncthreads();  // drains vmcnt (staging + A) and syncs LDS

  // ---- MFMA loop: B-frags from LDS (conflict-free b128, lane-linear)
  f32x4 acc[CT];
#pragma unroll
  for (int c = 0; c < CT; ++c) acc[c] = (f32x4){0.f, 0.f, 0.f, 0.f};
#pragma unroll
  for (int ks = 0; ks < KS; ++ks) {
#pragma unroll
    for (int c = 0; c < CT; ++c) {
      bf16x8 bfr = *(const bf16x8*)(Bls + ((c * KS + ks) * 64 + lane) * 8);
      acc[c] = __builtin_amdgcn_mfma_f32_16x16x32_bf16(af[ks], bfr, acc[c], 0, 0, 0);
    }
  }

  if constexpr (EPI == EP_RESID_LN) {
    static_assert(CT == 12);
#pragma unroll
    for (int c = 0; c < 12; ++c) {
      int col = c * 16 + lrow;
      float bia = bias[col];
#pragma unroll
      for (int i = 0; i < 4; ++i) {
        int row = rb + lkg * 4 + i;
        acc[c][i] += bia + resid[(size_t)row * 192 + col];
        ((float*)C0v)[(size_t)row * 192 + col] = acc[c][i];
      }
    }
#pragma unroll
    for (int i = 0; i < 4; ++i) {
      int row = rb + lkg * 4 + i;
      float s2 = 0.f;
#pragma unroll
      for (int c = 0; c < 12; ++c) s2 += acc[c][i];
      s2 += __shfl_xor(s2, 1); s2 += __shfl_xor(s2, 2);
      s2 += __shfl_xor(s2, 4); s2 += __shfl_xor(s2, 8);
      float mean = s2 * (1.f / 192.f);
      float vs2 = 0.f;
#pragma unroll
      for (int c = 0; c < 12; ++c) { float d = acc[c][i] - mean; vs2 += d * d; }
      vs2 += __shfl_xor(vs2, 1); vs2 += __shfl_xor(vs2, 2);
      vs2 += __shfl_xor(vs2, 4); vs2 += __shfl_xor(vs2, 8);
      float rstd = rsqrtf(vs2 * (1.f / 192.f) + 1e-5f);
#pragma unroll
      for (int c = 0; c < 12; ++c) {
        int col = c * 16 + lrow;
        ((short*)C1v)[(size_t)row * 192 + col] =
            f2bf((acc[c][i] - mean) * rstd * lg[col] + lb[col]);
      }
    }
  } else {
#pragma unroll
    for (int c = 0; c < CT; ++c) {
      int col = nb + c * 16 + lrow;
      float bia = bias[col];
#pragma unroll
      for (int i = 0; i < 4; ++i) {
        int row = rb + lkg * 4 + i;
        float v = acc[c][i] + bia;
        if constexpr (EPI == EP_Q) {
          ((short*)C0v)[(size_t)row * NTOT + col] = f2bf(v * 0.36067376022224085f);
        } else if constexpr (EPI == EP_KV) {
          if (col < 192) ((short*)C0v)[(size_t)row * 192 + col] = f2bf(v);
          else           ((short*)C1v)[(size_t)row * 192 + col - 192] = f2bf(v);
        } else if constexpr (EPI == EP_RESID) {
          ((float*)C0v)[(size_t)row * NTOT + col] = v + resid[(size_t)row * NTOT + col];
        } else {  // EP_GELU
          float gg = 0.5f * v * (1.f + erff(v * 0.70710678118654752f));
          ((short*)C0v)[(size_t)row * NTOT + col] = f2bf(gg);
        }
      }
    }
  }
}

// ---------------- Attention: 1 wave per (window, head), barrier-free ---------
// Q pre-scaled: softmax = exp2(s) directly, no max pass (|s| << overflow).
__global__ __launch_bounds__(128, 3) void attn_mfma(const short* __restrict__ qbuf,
                                                    const short* __restrict__ kbuf,
                                                    const short* __restrict__ vbuf,
                                                    const int* __restrict__ gIdx,
                                                    short* __restrict__ obuf) {
  __shared__ __align__(16) short VsS[2][224 * 16];
  __shared__ __align__(16) short PsS[2][8 * 232];

  const int tid = threadIdx.x;
  const int wv = tid >> 6;
  const int lane = tid & 63;
  const int lrow = lane & 15, lkg = lane >> 4;

  unsigned bid = blockIdx.x;
  unsigned u = (bid & 7u) * 3072u + (bid >> 3);  // bijective, 24576 blocks
  int w = (int)(u / 6u);
  int h = (int)(u % 6u) * 2 + wv;
  const int ww = w & 15, wh = (w >> 4) & 15, wd = w >> 8;

  short* Vs = VsS[wv];
  short* Ps = PsS[wv];
  const int* gw = gIdx + (size_t)w * 224;

  // index prefetch (batched 4B loads, L2-resident table)
  int ti[14];
#pragma unroll
  for (int T = 0; T < 14; ++T) ti[T] = gw[T * 16 + lrow];
  int mv[14];
#pragma unroll
  for (int k = 0; k < 14; ++k) mv[k] = gw[(lane >> 2) + k * 16];

  // Q fragment direct (bf16x8, 16B; pre-scaled by 0.25*log2e)
  bf16x8 qa = (bf16x8)0;
  if (lrow < 8 && lkg < 2) {
    int ldq = lrow >> 2, lhq = (lrow >> 1) & 1, lwq = lrow & 1;
    int tq = ((wd * 2 + ldq) * 32 + (wh * 2 + lhq)) * 32 + (ww * 2 + lwq);
    qa = *(const bf16x8*)(qbuf + (size_t)tq * 192 + h * 16 + lkg * 8);
  }

  // K frags: 14 branch-free gathers issued back-to-back
  bf16x8 kf[14];
#pragma unroll
  for (int T = 0; T < 14; ++T) {
    kf[T] = (bf16x8)0;
    if (lkg < 2)
      kf[T] = *(const bf16x8*)(kbuf + (size_t)ti[T] * 192 + h * 16 + lkg * 8);
  }

  // QK^T
  f32x4 s[14];
  const f32x4 zero4 = {0.f, 0.f, 0.f, 0.f};
#pragma unroll
  for (int T = 0; T < 14; ++T)
    s[T] = __builtin_amdgcn_mfma_f32_16x16x32_bf16(qa, kf[T], zero4, 0, 0, 0);
  if (lrow >= 8) {  // mask padded tokens 216..223 -> exp2(-1e30)=0
    s[13][0] = -1e30f; s[13][1] = -1e30f; s[13][2] = -1e30f; s[13][3] = -1e30f;
  }

  // V loads issued now; latency hides under softmax + P-pack
  const int q4c = (lane & 3) * 4;
  bf16x4 vv[14];
#pragma unroll
  for (int k = 0; k < 14; ++k)
    vv[k] = *(const bf16x4*)(vbuf + (size_t)mv[k] * 192 + h * 16 + q4c);

  // softmax: p = exp2(s) (Q pre-scaled), sum-reduce over 16-lane groups
  float inv[4];
#pragma unroll
  for (int r = 0; r < 4; ++r) {
    float sum = 0.f;
#pragma unroll
    for (int t = 0; t < 14; ++t) {
      float p = exp2f(s[t][r]);
      s[t][r] = p;
      sum += p;
    }
    sum += __shfl_xor(sum, 1);
    sum += __shfl_xor(sum, 2);
    sum += __shfl_xor(sum, 4);
    sum += __shfl_xor(sum, 8);
    inv[r] = 1.f / sum;
  }

  // P -> LDS: plain b16 scalar stores
  if (lane < 32) {
    const int rbase = (lane >> 4) * 4;
    short* Pw = Ps + lrow;
#pragma unroll
    for (int r = 0; r < 4; ++r)
#pragma unroll
      for (int t = 0; t < 14; ++t)
        Pw[(rbase + r) * 232 + t * 16] = f2bf(s[t][r]);
  }

  // V -> LDS (token-major [224][16]), linear 8B writes
#pragma unroll
  for (int k = 0; k < 14; ++k)
    *(bf16x4*)(Vs + ((unsigned)lane + (unsigned)k * 64u) * 4u) = vv[k];
  asm volatile("s_waitcnt lgkmcnt(0)" ::: "memory");
  __builtin_amdgcn_sched_barrier(0);

  // PV: tr-reads + P frags, single wait, 7 MFMA
  unsigned vbase = (unsigned)(size_t)((__attribute__((address_space(3))) short*)Vs)
                 + (unsigned)(lkg * 256 + (lrow >> 2) * 32 + (lane & 3) * 8);
  bf16x4 t0[7], t1[7];
#pragma unroll
  for (int T = 0; T < 7; ++T) {
    unsigned a = vbase + (unsigned)(T * 1024);
    asm volatile("ds_read_b64_tr_b16 %0, %1" : "=v"(t0[T]) : "v"(a));
    asm volatile("ds_read_b64_tr_b16 %0, %1 offset:128" : "=v"(t1[T]) : "v"(a));
  }
  bf16x8 pa[7];
#pragma unroll
  for (int T = 0; T < 7; ++T) {
    pa[T] = (bf16x8)0;
    if (lrow < 8) pa[T] = *(const bf16x8*)(Ps + lrow * 232 + T * 32 + lkg * 8);
  }
  asm volatile("s_waitcnt lgkmcnt(0)" ::: "memory");
  __builtin_amdgcn_sched_barrier(0);
  f32x4 o = {0.f, 0.f, 0.f, 0.f};
#pragma unroll
  for (int T = 0; T < 7; ++T) {
    bf16x8 vf = __builtin_shufflevector(t0[T], t1[T], 0, 1, 2, 3, 4, 5, 6, 7);
    o = __builtin_amdgcn_mfma_f32_16x16x32_bf16(pa[T], vf, o, 0, 0, 0);
  }

  // store O (bf16, normalized)
  if (lane < 32) {
#pragma unroll
    for (int r = 0; r < 4; ++r) {
      int n = (lane >> 4) * 4 + r;
      int ldq = n >> 2, lhq = (n >> 1) & 1, lwq = n & 1;
      int tq = ((wd * 2 + ldq) * 32 + (wh * 2 + lhq)) * 32 + (ww * 2 + lwq);
      obuf[(size_t)tq * 192 + h * 16 + lrow] = f2bf(o[r] * inv[r]);
    }
  }
}

extern "C" void kernel_launch(void* const* d_in, const int* in_sizes, int n_in,
                              void* d_out, int out_size, void* d_ws, size_t ws_size,
                              hipStream_t stream) {
  const float* x   = (const float*)d_in[0];
  const float* xa  = (const float*)d_in[1];
  const float* n1g = (const float*)d_in[2];
  const float* n1b = (const float*)d_in[3];
  const float* n2g = (const float*)d_in[4];
  const float* n2b = (const float*)d_in[5];
  const float* Wq  = (const float*)d_in[6];
  const float* bq  = (const float*)d_in[7];
  const float* Wkv = (const float*)d_in[8];
  const float* bkv = (const float*)d_in[9];
  const float* Wp  = (const float*)d_in[10];
  const float* bp  = (const float*)d_in[11];
  const float* W1  = (const float*)d_in[12];
  const float* b1  = (const float*)d_in[13];
  const float* W2  = (const float*)d_in[14];
  const float* b2  = (const float*)d_in[15];

  char* wsb = (char*)d_ws;
  const size_t BB = (size_t)TOK * 192 * 2;  // 12.58 MB bf16 token buffer
  short* attn_o = (short*)(wsb + 0 * BB);
  short* xn2    = (short*)(wsb + 1 * BB);               // LN2 out (bf16)
  short* qb     = (short*)(wsb + 2 * BB);               // Q; later hmlp spans qb..kb
  short* kb     = (short*)(wsb + 3 * BB);               // K + ext row TOK
  short* vb     = (short*)(wsb + 4 * BB + 4096);        // V + ext row TOK
  float* x1     = (float*)(wsb + 5 * BB + 8192);        // f32 [TOK][192] (2*BB)
  char* p = wsb + 7 * BB + 16384;
  int* gIdx = (int*)p;            p += (size_t)NWIN * 224 * 4;
  short* wq_p  = (short*)p;       p += 192 * 192 * 2;
  short* wkv_p = (short*)p;       p += 192 * 384 * 2;
  short* wp_p  = (short*)p;       p += 192 * 192 * 2;
  short* w1_p  = (short*)p;       p += 192 * 384 * 2;
  short* w2_p  = (short*)p;       p += 384 * 192 * 2;

  short* hmlp = qb;  // [TOK][384] bf16 spans qb(BB) + kb region

  prep_kernel<<<144 + NWIN + 1, 256, 0, stream>>>(
      Wq, Wkv, Wp, W1, W2, bkv, wq_p, wkv_p, wp_p, w1_p, w2_p,
      kb + (size_t)TOK * 192, vb + (size_t)TOK * 192, gIdx);

  // Q = (LN1(x)@Wq+bq)*0.25*log2e ; K,V = LN1(xa)@Wkv+bkv
  gemm_mfma<EP_Q, true, 12, 192, 192><<<dim3(512, 1), 256, 0, stream>>>(
      x, wq_p, bq, nullptr, n1g, n1b, qb, nullptr);
  gemm_mfma<EP_KV, true, 12, 192, 384><<<dim3(512, 2), 256, 0, stream>>>(
      xa, wkv_p, bkv, nullptr, n1g, n1b, kb, vb);

  attn_mfma<<<NWIN * 6, 128, 0, stream>>>(qb, kb, vb, gIdx, attn_o);

  // x1 = x + attn_o@Wp+bp ; xn2 = LN2(x1)
  gemm_mfma<EP_RESID_LN, false, 12, 192, 192><<<dim3(512, 1), 256, 0, stream>>>(
      attn_o, wp_p, bp, x, n2g, n2b, x1, xn2);

  gemm_mfma<EP_GELU, false, 12, 192, 384><<<dim3(512, 2), 256, 0, stream>>>(
      xn2, w1_p, b1, nullptr, nullptr, nullptr, hmlp, nullptr);
  gemm_mfma<EP_RESID, false, 6, 384, 192><<<dim3(512, 2), 256, 0, stream>>>(
      hmlp, w2_p, b2, x1, nullptr, nullptr, (float*)d_out, nullptr);
}